// Round 12
// baseline (140.571 us; speedup 1.0000x reference)
//
#include <hip/hip_runtime.h>

#define NTOT 4096
#define CH 256
#define SCALE 0.0390625f   // 1/(256*0.1)
#define LAM 0.001f

typedef unsigned short u16;
typedef __attribute__((ext_vector_type(8))) short short8;   // 8 bf16 (4 VGPRs)
typedef __attribute__((ext_vector_type(4))) float floatx4;  // MFMA acc

__device__ __forceinline__ float wave_sum64(float v) {
  #pragma unroll
  for (int o = 32; o; o >>= 1) v += __shfl_down(v, o, 64);
  return v;
}
__device__ __forceinline__ u16 f2bf(float f) {  // round-to-nearest-even
  unsigned u = __float_as_uint(f);
  u += 0x7fffu + ((u >> 16) & 1u);
  return (u16)(u >> 16);
}
__device__ __forceinline__ float bf2f(u16 h) {
  return __uint_as_float(((unsigned)h) << 16);
}
__device__ __forceinline__ void gload_lds(const u16* g, void* l) {
  __builtin_amdgcn_global_load_lds((const __attribute__((address_space(1))) void*)g,
                                   (__attribute__((address_space(3))) void*)l, 16, 0, 0);
}
// 128 B LDS rows: byte ^= (row&7)<<4 (verified rounds 6-11, conflicts -> 0)
__device__ __forceinline__ int swz128(int row) { return (row & 7) << 4; }

// f32 -> bf16 for both inputs + row norms of the ROUNDED values (one wave/row).
__global__ __launch_bounds__(64) void cvt_norm_k(const float* __restrict__ a,
                                                 const float* __restrict__ b,
                                                 u16* __restrict__ ab, u16* __restrict__ bb,
                                                 float* __restrict__ na, float* __restrict__ nb) {
  int row = blockIdx.x;
  const float* src; u16* dst; float* nd;
  if (row < NTOT) { src = a; dst = ab; nd = na; }
  else { row -= NTOT; src = b; dst = bb; nd = nb; }
  const float4 v = *reinterpret_cast<const float4*>(src + (size_t)row * CH + threadIdx.x * 4);
  const u16 h0 = f2bf(v.x), h1 = f2bf(v.y), h2 = f2bf(v.z), h3 = f2bf(v.w);
  uint2 st;
  st.x = (unsigned)h0 | ((unsigned)h1 << 16);
  st.y = (unsigned)h2 | ((unsigned)h3 << 16);
  *reinterpret_cast<uint2*>(dst + (size_t)row * CH + threadIdx.x * 4) = st;
  const float f0 = bf2f(h0), f1 = bf2f(h1), f2 = bf2f(h2), f3 = bf2f(h3);
  float s = f0 * f0 + f1 * f1 + f2 * f2 + f3 * f3;
  s = wave_sum64(s);
  if (threadIdx.x == 0) nd[row] = s;
}

// [4096][256] -> [256][4096] bf16 transpose for both inputs (z selects a/b)
__global__ __launch_bounds__(256) void transpose2_k(const u16* __restrict__ ab,
                                                    const u16* __restrict__ bb,
                                                    u16* __restrict__ at, u16* __restrict__ bt) {
  const u16* __restrict__ src = blockIdx.z ? bb : ab;
  u16* __restrict__ dst = blockIdx.z ? bt : at;
  __shared__ u16 t[32][33];
  const int bx = blockIdx.x * 32, by = blockIdx.y * 32;
  const int lx = threadIdx.x & 31, ly = threadIdx.x >> 5;
  #pragma unroll
  for (int i = 0; i < 32; i += 8)
    t[ly + i][lx] = src[(size_t)(by + ly + i) * CH + bx + lx];
  __syncthreads();
  #pragma unroll
  for (int i = 0; i < 32; i += 8)
    dst[(size_t)(bx + ly + i) * NTOT + by + lx] = t[lx][ly + i];
}

// ---------------------------------------------------------------------------
// Phase-1 GEMM+exp, 256x256 tile, 8 waves (2M x 4N), wave tile 128x64.
// Halves the operand re-read factor (32x -> 16x): L3 traffic 256 -> 128 MB.
// LDS 128 KB (1 block/CU = 8 waves/CU, same as before). BK=64, dbuf,
// verified 128B-row swizzle (source-side + read-side).
__global__ __launch_bounds__(512, 2) void gemm_exp_k(const u16* __restrict__ abf,
                                                     const u16* __restrict__ bbf,
                                                     const float* __restrict__ na,
                                                     const float* __restrict__ nb,
                                                     u16* __restrict__ E,
                                                     float* __restrict__ dnp) {
  const int bx = blockIdx.x, by = blockIdx.y, dir = blockIdx.z;
  const u16* __restrict__ A = dir ? bbf : abf;
  const u16* __restrict__ B = dir ? abf : bbf;
  const float* __restrict__ ny = dir ? na : nb;
  E += (size_t)dir * NTOT * NTOT;
  dnp += (size_t)dir * NTOT * 64;

  __shared__ u16 As[2][256][64];   // 32 KB per buffer
  __shared__ u16 Bs[2][256][64];
  const int tid = threadIdx.x, wid = tid >> 6, lane = tid & 63;
  const int bm = by * 256, bn = bx * 256;
  const int wr = (wid >> 2) * 128;          // wave M offset (2 rows of waves)
  const int wc = (wid & 3) * 64;            // wave N offset (4 cols of waves)
  const int lr = lane & 15, g = lane >> 4;

  auto stage = [&](int t, int bi) {   // 8 gload/lane: 32 KB A + 32 KB B
    const int k0 = t * 64;
    #pragma unroll
    for (int i = 0; i < 4; ++i) {
      const int lb = (wid + 8 * i) * 1024;
      const int db = lb + lane * 16;
      const int r = db >> 7;
      const int cb = (db & 127) ^ swz128(r);
      gload_lds(A + (size_t)(bm + r) * CH + k0 + (cb >> 1), (char*)&As[bi][0][0] + lb);
      gload_lds(B + (size_t)(bn + r) * CH + k0 + (cb >> 1), (char*)&Bs[bi][0][0] + lb);
    }
  };

  floatx4 acc[8][4] = {};
  stage(0, 0);
  asm volatile("s_waitcnt vmcnt(0)" ::: "memory");
  __builtin_amdgcn_s_barrier();
  #pragma unroll
  for (int t = 0; t < 4; ++t) {
    if (t < 3) stage(t + 1, (t + 1) & 1);
    const int bi = t & 1;
    const char* Ab = (const char*)&As[bi][0][0];
    const char* Bb = (const char*)&Bs[bi][0][0];
    #pragma unroll
    for (int ks = 0; ks < 2; ++ks) {
      const int ob = ks * 64 + g * 16;
      short8 af[8], bfr[4];
      #pragma unroll
      for (int m = 0; m < 8; ++m) {
        const int row = wr + m * 16 + lr;
        af[m] = *reinterpret_cast<const short8*>(Ab + row * 128 + (ob ^ swz128(row)));
      }
      #pragma unroll
      for (int n = 0; n < 4; ++n) {
        const int row = wc + n * 16 + lr;
        bfr[n] = *reinterpret_cast<const short8*>(Bb + row * 128 + (ob ^ swz128(row)));
      }
      #pragma unroll
      for (int m = 0; m < 8; ++m)
        #pragma unroll
        for (int n = 0; n < 4; ++n)
          acc[m][n] = __builtin_amdgcn_mfma_f32_16x16x32_bf16(af[m], bfr[n], acc[m][n], 0, 0, 0);
    }
    if (t < 3) {
      asm volatile("s_waitcnt vmcnt(0)" ::: "memory");
      __builtin_amdgcn_s_barrier();
    }
  }
  // epilogue: w = exp(logit), write bf16 E, per-row partial sums
  float nyv[4];
  #pragma unroll
  for (int n = 0; n < 4; ++n) nyv[n] = ny[bn + wc + n * 16 + lr];
  #pragma unroll
  for (int m = 0; m < 8; ++m) {
    const int rowb = bm + wr + m * 16 + g * 4;
    float rowsum[4] = {};
    #pragma unroll
    for (int n = 0; n < 4; ++n) {
      const int col = bn + wc + n * 16 + lr;
      #pragma unroll
      for (int r = 0; r < 4; ++r) {
        const float w = __expf((2.f * acc[m][n][r] - nyv[n]) * SCALE);
        E[(size_t)(rowb + r) * NTOT + col] = f2bf(w);
        rowsum[r] += w;
      }
    }
    #pragma unroll
    for (int r = 0; r < 4; ++r) {
      float s = rowsum[r];
      #pragma unroll
      for (int o = 1; o < 16; o <<= 1) s += __shfl_xor(s, o, 64);
      if (lr == 0) dnp[(size_t)(rowb + r) * 64 + bx * 4 + (wid & 3)] = s;
    }
  }
}

// ---------------------------------------------------------------------------
// Qp = E . Yt^T, split-K 4, both dirs (round-10 structure, XCD-pinned dk).
// Not the bottleneck (~16 us) -- unchanged.
__global__ __launch_bounds__(256, 2) void gemm_qp_k(const u16* __restrict__ E,
                                                    const u16* __restrict__ att,
                                                    const u16* __restrict__ btt,
                                                    float* __restrict__ Qp) {
  const int wg = blockIdx.x;
  const int dk = wg & 7;
  const int j = wg >> 3;
  const int dir = dk >> 2, kz = dk & 3;
  const int bxi = j & 1, byi = j >> 1;

  const u16* __restrict__ A = E + (size_t)dir * NTOT * NTOT;
  const u16* __restrict__ B = dir ? att : btt;
  float* __restrict__ C = Qp + (size_t)dir * 4 * NTOT * CH + (size_t)kz * NTOT * CH;
  const int k0base = kz * (NTOT / 4);

  __shared__ u16 As[2][128][64];
  __shared__ u16 Bs[2][128][64];
  const int tid = threadIdx.x, wid = tid >> 6, lane = tid & 63;
  const int bn = bxi * 128, bm = byi * 128;
  const int wr = (wid >> 1) * 64, wc = (wid & 1) * 64;
  const int lr = lane & 15;

  auto stage = [&](int t, int bi) {
    const int k0 = k0base + t * 64;
    #pragma unroll
    for (int i = 0; i < 4; ++i) {
      const int lb = (wid + 4 * i) * 1024;
      const int db = lb + lane * 16;
      const int r = db >> 7;
      const int cb = (db & 127) ^ swz128(r);
      gload_lds(A + (size_t)(bm + r) * NTOT + k0 + (cb >> 1), (char*)&As[bi][0][0] + lb);
      gload_lds(B + (size_t)(bn + r) * NTOT + k0 + (cb >> 1), (char*)&Bs[bi][0][0] + lb);
    }
  };

  floatx4 acc[4][4] = {};
  stage(0, 0);
  asm volatile("s_waitcnt vmcnt(0)" ::: "memory");
  __builtin_amdgcn_s_barrier();
  for (int t = 0; t < 16; ++t) {
    if (t < 15) stage(t + 1, (t + 1) & 1);
    const int bi = t & 1;
    const char* Ab = (const char*)&As[bi][0][0];
    const char* Bb = (const char*)&Bs[bi][0][0];
    #pragma unroll
    for (int ks = 0; ks < 2; ++ks) {
      const int ob = ks * 64 + (lane >> 4) * 16;
      short8 af[4], bfr[4];
      #pragma unroll
      for (int m = 0; m < 4; ++m) {
        const int row = wr + m * 16 + lr;
        af[m] = *reinterpret_cast<const short8*>(Ab + row * 128 + (ob ^ swz128(row)));
      }
      #pragma unroll
      for (int n = 0; n < 4; ++n) {
        const int row = wc + n * 16 + lr;
        bfr[n] = *reinterpret_cast<const short8*>(Bb + row * 128 + (ob ^ swz128(row)));
      }
      #pragma unroll
      for (int m = 0; m < 4; ++m)
        #pragma unroll
        for (int n = 0; n < 4; ++n)
          acc[m][n] = __builtin_amdgcn_mfma_f32_16x16x32_bf16(af[m], bfr[n], acc[m][n], 0, 0, 0);
    }
    asm volatile("s_waitcnt vmcnt(0)" ::: "memory");
    __builtin_amdgcn_s_barrier();
  }
  #pragma unroll
  for (int m = 0; m < 4; ++m) {
    const int row = bm + wr + m * 16 + (lane >> 4) * 4;
    #pragma unroll
    for (int n = 0; n < 4; ++n) {
      const int col = bn + wc + n * 16 + lr;
      #pragma unroll
      for (int r = 0; r < 4; ++r)
        C[(size_t)(row + r) * CH + col] = acc[m][n][r];
    }
  }
}

// Q = (sum of 4 split-K partials) / dn -> bf16. Block per row; both dirs via z.
__global__ __launch_bounds__(256) void reduce_q_k(const float* __restrict__ Qp,
                                                  const float* __restrict__ dnp,
                                                  u16* __restrict__ Qb) {
  const int dir = blockIdx.z;
  Qp += (size_t)dir * 4 * NTOT * CH;
  dnp += (size_t)dir * NTOT * 64;
  Qb += (size_t)dir * NTOT * CH;
  const int row = blockIdx.x, tid = threadIdx.x;
  __shared__ float sdn;
  if (tid < 64) {
    float s = dnp[(size_t)row * 64 + tid];
    s = wave_sum64(s);
    if (tid == 0) sdn = 1.0f / s;
  }
  __syncthreads();
  const float rdn = sdn;
  const size_t o = (size_t)row * CH + tid;
  const size_t st = (size_t)NTOT * CH;
  const float q = (Qp[o] + Qp[o + st] + Qp[o + 2 * st] + Qp[o + 3 * st]) * rdn;
  Qb[o] = f2bf(q);
}

// ---------------------------------------------------------------------------
// Phase-2 flash, 256x256 tile (same skeleton as gemm_exp_k). T never
// materialized; epilogue folds s0, s1=sum w*(idx-c), s2=sum w*(idx-c)^2.
__global__ __launch_bounds__(512, 2) void flash_stats_k(const u16* __restrict__ Qball,
                                                        const u16* __restrict__ abf,
                                                        const u16* __restrict__ bbf,
                                                        const float* __restrict__ na,
                                                        const float* __restrict__ nb,
                                                        const float* __restrict__ idxa,
                                                        const float* __restrict__ idxb,
                                                        float4* __restrict__ statsp) {
  const int bx = blockIdx.x, by = blockIdx.y, dir = blockIdx.z;
  const u16* __restrict__ Qb = Qball + (size_t)dir * NTOT * CH;
  const u16* __restrict__ X = dir ? bbf : abf;
  const float* __restrict__ nx = dir ? nb : na;
  const float* __restrict__ idx = dir ? idxb : idxa;
  statsp += (size_t)dir * NTOT * 64;

  __shared__ u16 As[2][256][64];
  __shared__ u16 Bs[2][256][64];
  const int tid = threadIdx.x, wid = tid >> 6, lane = tid & 63;
  const int bm = by * 256, bn = bx * 256;
  const int wr = (wid >> 2) * 128;
  const int wc = (wid & 3) * 64;
  const int lr = lane & 15, g = lane >> 4;

  auto stage = [&](int t, int bi) {
    const int k0 = t * 64;
    #pragma unroll
    for (int i = 0; i < 4; ++i) {
      const int lb = (wid + 8 * i) * 1024;
      const int db = lb + lane * 16;
      const int r = db >> 7;
      const int cb = (db & 127) ^ swz128(r);
      gload_lds(Qb + (size_t)(bm + r) * CH + k0 + (cb >> 1), (char*)&As[bi][0][0] + lb);
      gload_lds(X + (size_t)(bn + r) * CH + k0 + (cb >> 1), (char*)&Bs[bi][0][0] + lb);
    }
  };

  floatx4 acc[8][4] = {};
  stage(0, 0);
  asm volatile("s_waitcnt vmcnt(0)" ::: "memory");
  __builtin_amdgcn_s_barrier();
  #pragma unroll
  for (int t = 0; t < 4; ++t) {
    if (t < 3) stage(t + 1, (t + 1) & 1);
    const int bi = t & 1;
    const char* Ab = (const char*)&As[bi][0][0];
    const char* Bb = (const char*)&Bs[bi][0][0];
    #pragma unroll
    for (int ks = 0; ks < 2; ++ks) {
      const int ob = ks * 64 + g * 16;
      short8 af[8], bfr[4];
      #pragma unroll
      for (int m = 0; m < 8; ++m) {
        const int row = wr + m * 16 + lr;
        af[m] = *reinterpret_cast<const short8*>(Ab + row * 128 + (ob ^ swz128(row)));
      }
      #pragma unroll
      for (int n = 0; n < 4; ++n) {
        const int row = wc + n * 16 + lr;
        bfr[n] = *reinterpret_cast<const short8*>(Bb + row * 128 + (ob ^ swz128(row)));
      }
      #pragma unroll
      for (int m = 0; m < 8; ++m)
        #pragma unroll
        for (int n = 0; n < 4; ++n)
          acc[m][n] = __builtin_amdgcn_mfma_f32_16x16x32_bf16(af[m], bfr[n], acc[m][n], 0, 0, 0);
    }
    if (t < 3) {
      asm volatile("s_waitcnt vmcnt(0)" ::: "memory");
      __builtin_amdgcn_s_barrier();
    }
  }
  // epilogue: fold stats per m-row-group (keeps register pressure bounded)
  float nxv[4], iv[4];
  #pragma unroll
  for (int n = 0; n < 4; ++n) {
    const int col = bn + wc + n * 16 + lr;
    nxv[n] = nx[col];
    iv[n] = idx[col];
  }
  #pragma unroll
  for (int m = 0; m < 8; ++m) {
    const int rowb = bm + wr + m * 16 + g * 4;
    float s0[4] = {}, s1[4] = {}, s2[4] = {};
    #pragma unroll
    for (int r = 0; r < 4; ++r) {
      const float cen = idx[rowb + r];
      #pragma unroll
      for (int n = 0; n < 4; ++n) {
        const float w = __expf((2.f * acc[m][n][r] - nxv[n]) * SCALE);
        const float d = iv[n] - cen;
        s0[r] += w;
        s1[r] += w * d;
        s2[r] += w * d * d;
      }
    }
    #pragma unroll
    for (int r = 0; r < 4; ++r) {
      float av = s0[r], bv = s1[r], cv = s2[r];
      #pragma unroll
      for (int o = 1; o < 16; o <<= 1) {
        av += __shfl_xor(av, o, 64);
        bv += __shfl_xor(bv, o, 64);
        cv += __shfl_xor(cv, o, 64);
      }
      if (lr == 0)
        statsp[(size_t)(rowb + r) * 64 + bx * 4 + (wid & 3)] = make_float4(av, bv, cv, 0.f);
    }
  }
}

// per-row: combine 64 partials -> loss term. mu = S1/S0; var = S2/S0 - mu^2.
__global__ __launch_bounds__(256) void stats_combine_k(const float4* __restrict__ statsp,
                                                       float* __restrict__ terms) {
  const int row = blockIdx.x * 256 + threadIdx.x;   // 0..2*NTOT-1
  float S0 = 0.f, S1 = 0.f, S2 = 0.f;
  #pragma unroll
  for (int p = 0; p < 64; ++p) {
    const float4 v = statsp[(size_t)row * 64 + p];
    S0 += v.x; S1 += v.y; S2 += v.z;
  }
  const float mu = S1 / S0;
  const float var = S2 / S0 - mu * mu;
  terms[row] = mu * mu / var + LAM * logf(var);
}

__global__ __launch_bounds__(256) void final_reduce_k(const float* __restrict__ terms,
                                                      float* __restrict__ out) {
  float s = 0.f;
  for (int i = threadIdx.x; i < 2 * NTOT; i += 256) s += terms[i];
  __shared__ float red[4];
  s = wave_sum64(s);
  if ((threadIdx.x & 63) == 0) red[threadIdx.x >> 6] = s;
  __syncthreads();
  if (threadIdx.x == 0) out[0] = (red[0] + red[1] + red[2] + red[3]) * (1.0f / (2.0f * NTOT));
}

extern "C" void kernel_launch(void* const* d_in, const int* in_sizes, int n_in,
                              void* d_out, int out_size, void* d_ws, size_t ws_size,
                              hipStream_t stream) {
  const float* a    = (const float*)d_in[0];
  const float* b    = (const float*)d_in[1];
  const float* idxa = (const float*)d_in[2];
  const float* idxb = (const float*)d_in[3];
  float* out = (float*)d_out;
  char* ws = (char*)d_ws;

  size_t off = 0;
  u16*    E    = (u16*)(ws + off);    off += 2 * (size_t)NTOT * NTOT * 2;   // 64 MB
  float*  Qp   = (float*)(ws + off);  off += 2 * 4 * (size_t)NTOT * CH * 4; // 32 MB
  u16*    Qb   = (u16*)(ws + off);    off += 2 * (size_t)NTOT * CH * 2;     // 4 MB
  u16*    abf  = (u16*)(ws + off);    off += (size_t)NTOT * CH * 2;
  u16*    bbf  = (u16*)(ws + off);    off += (size_t)NTOT * CH * 2;
  u16*    att  = (u16*)(ws + off);    off += (size_t)NTOT * CH * 2;
  u16*    btt  = (u16*)(ws + off);    off += (size_t)NTOT * CH * 2;
  float*  na   = (float*)(ws + off);  off += (size_t)NTOT * 4;
  float*  nb   = (float*)(ws + off);  off += (size_t)NTOT * 4;
  float*  dnp  = (float*)(ws + off);  off += 2 * (size_t)NTOT * 64 * 4;     // 2 MB
  float4* stp  = (float4*)(ws + off); off += 2 * (size_t)NTOT * 64 * 16;    // 8 MB
  float*  terms = (float*)(ws + off);

  cvt_norm_k<<<2 * NTOT, 64, 0, stream>>>(a, b, abf, bbf, na, nb);
  transpose2_k<<<dim3(CH / 32, NTOT / 32, 2), 256, 0, stream>>>(abf, bbf, att, btt);
  gemm_exp_k<<<dim3(16, 16, 2), 512, 0, stream>>>(abf, bbf, na, nb, E, dnp);
  gemm_qp_k<<<512, 256, 0, stream>>>(E, att, btt, Qp);
  reduce_q_k<<<dim3(NTOT, 1, 2), 256, 0, stream>>>(Qp, dnp, Qb);
  flash_stats_k<<<dim3(16, 16, 2), 512, 0, stream>>>(Qb, abf, bbf, na, nb, idxa, idxb, stp);
  stats_combine_k<<<2 * NTOT / 256, 256, 0, stream>>>(stp, terms);
  final_reduce_k<<<1, 256, 0, stream>>>(terms, out);
}

// Round 13
// 125.040 us; speedup vs baseline: 1.1242x; 1.1242x over previous
//
#include <hip/hip_runtime.h>

#define NTOT 4096
#define CH 256
#define SCALE 0.0390625f   // 1/(256*0.1)
#define LAM 0.001f

typedef unsigned short u16;
typedef __attribute__((ext_vector_type(8))) short short8;   // 8 bf16 (4 VGPRs)
typedef __attribute__((ext_vector_type(4))) float floatx4;  // MFMA acc

__device__ __forceinline__ float wave_sum64(float v) {
  #pragma unroll
  for (int o = 32; o; o >>= 1) v += __shfl_down(v, o, 64);
  return v;
}
__device__ __forceinline__ u16 f2bf(float f) {  // round-to-nearest-even
  unsigned u = __float_as_uint(f);
  u += 0x7fffu + ((u >> 16) & 1u);
  return (u16)(u >> 16);
}
__device__ __forceinline__ float bf2f(u16 h) {
  return __uint_as_float(((unsigned)h) << 16);
}
__device__ __forceinline__ void gload_lds(const u16* g, void* l) {
  __builtin_amdgcn_global_load_lds((const __attribute__((address_space(1))) void*)g,
                                   (__attribute__((address_space(3))) void*)l, 16, 0, 0);
}
__device__ __forceinline__ void mm4x4(const short8 (&av)[4], const short8 (&bv)[4],
                                      floatx4 (&acc)[4][4]) {
  #pragma unroll
  for (int m = 0; m < 4; ++m)
    #pragma unroll
    for (int n = 0; n < 4; ++n)
      acc[m][n] = __builtin_amdgcn_mfma_f32_16x16x32_bf16(av[m], bv[n], acc[m][n], 0, 0, 0);
}
// 128 B LDS rows: byte ^= (row&7)<<4 (verified rounds 6-12, conflicts -> 0)
__device__ __forceinline__ int swz128(int row) { return (row & 7) << 4; }

// f32 -> bf16 for both inputs + row norms of the ROUNDED values (one wave/row).
__global__ __launch_bounds__(64) void cvt_norm_k(const float* __restrict__ a,
                                                 const float* __restrict__ b,
                                                 u16* __restrict__ ab, u16* __restrict__ bb,
                                                 float* __restrict__ na, float* __restrict__ nb) {
  int row = blockIdx.x;
  const float* src; u16* dst; float* nd;
  if (row < NTOT) { src = a; dst = ab; nd = na; }
  else { row -= NTOT; src = b; dst = bb; nd = nb; }
  const float4 v = *reinterpret_cast<const float4*>(src + (size_t)row * CH + threadIdx.x * 4);
  const u16 h0 = f2bf(v.x), h1 = f2bf(v.y), h2 = f2bf(v.z), h3 = f2bf(v.w);
  uint2 st;
  st.x = (unsigned)h0 | ((unsigned)h1 << 16);
  st.y = (unsigned)h2 | ((unsigned)h3 << 16);
  *reinterpret_cast<uint2*>(dst + (size_t)row * CH + threadIdx.x * 4) = st;
  const float f0 = bf2f(h0), f1 = bf2f(h1), f2 = bf2f(h2), f3 = bf2f(h3);
  float s = f0 * f0 + f1 * f1 + f2 * f2 + f3 * f3;
  s = wave_sum64(s);
  if (threadIdx.x == 0) nd[row] = s;
}

// [4096][256] -> [256][4096] bf16 transpose for both inputs (z selects a/b)
__global__ __launch_bounds__(256) void transpose2_k(const u16* __restrict__ ab,
                                                    const u16* __restrict__ bb,
                                                    u16* __restrict__ at, u16* __restrict__ bt) {
  const u16* __restrict__ src = blockIdx.z ? bb : ab;
  u16* __restrict__ dst = blockIdx.z ? bt : at;
  __shared__ u16 t[32][33];
  const int bx = blockIdx.x * 32, by = blockIdx.y * 32;
  const int lx = threadIdx.x & 31, ly = threadIdx.x >> 5;
  #pragma unroll
  for (int i = 0; i < 32; i += 8)
    t[ly + i][lx] = src[(size_t)(by + ly + i) * CH + bx + lx];
  __syncthreads();
  #pragma unroll
  for (int i = 0; i < 32; i += 8)
    dst[(size_t)(bx + ly + i) * NTOT + by + lx] = t[lx][ly + i];
}

// ---------------------------------------------------------------------------
// SHARED-S phase-1: one GEMM tile S = a_tile . b_tile^T serves BOTH directions.
// Epilogue produces E_ab[i][j] = exp((2S - nb_j)*SC) (direct store, as before)
// AND E_ba[j][i] = exp((2S - na_i)*SC) (dir-ba in natural [b][a] layout) via an
// LDS transpose that REUSES the staging buffers after the K-loop.
// Halves phase-1 GEMM FLOPs and staging traffic. dnp layouts unchanged.
__global__ __launch_bounds__(256, 2) void gemm_exp_k(const u16* __restrict__ abf,
                                                     const u16* __restrict__ bbf,
                                                     const float* __restrict__ na,
                                                     const float* __restrict__ nb,
                                                     u16* __restrict__ E,
                                                     float* __restrict__ dnp) {
  const int bx = blockIdx.x, by = blockIdx.y;
  const int bn = bx * 128, bm = by * 128;
  u16* __restrict__ Eab = E;                                // [a-row][b-col]
  u16* __restrict__ Eba = E + (size_t)NTOT * NTOT;          // [b-row][a-col]
  float* __restrict__ dnp0 = dnp;                           // ab row sums
  float* __restrict__ dnp1 = dnp + (size_t)NTOT * 64;       // ba row sums

  __shared__ u16 smem[32768];   // 64 KB: As dbuf [0,32KB), Bs dbuf [32KB,64KB)
  const int tid = threadIdx.x, wid = tid >> 6, lane = tid & 63;
  const int wr = (wid >> 1) * 64, wc = (wid & 1) * 64;
  const int lr = lane & 15, g = lane >> 4;

  auto stage = [&](int t, int bi) {
    const int k0 = t * 64;
    #pragma unroll
    for (int i = 0; i < 4; ++i) {
      const int lb = (wid + 4 * i) * 1024;          // wave-uniform LDS byte base
      const int db = lb + lane * 16;                // lane's linear dest byte
      const int r = db >> 7;                        // dest row (128 B rows)
      const int cb = (db & 127) ^ swz128(r);        // inverse-swizzled source col
      gload_lds(abf + (size_t)(bm + r) * CH + k0 + (cb >> 1), (char*)smem + bi * 16384 + lb);
      gload_lds(bbf + (size_t)(bn + r) * CH + k0 + (cb >> 1), (char*)smem + 32768 + bi * 16384 + lb);
    }
  };

  floatx4 acc[4][4] = {};
  stage(0, 0);
  asm volatile("s_waitcnt vmcnt(0)" ::: "memory");
  __builtin_amdgcn_s_barrier();
  #pragma unroll
  for (int t = 0; t < 4; ++t) {
    if (t < 3) stage(t + 1, (t + 1) & 1);
    const int bi = t & 1;
    const char* Ab = (const char*)smem + bi * 16384;
    const char* Bb = (const char*)smem + 32768 + bi * 16384;
    #pragma unroll
    for (int ks = 0; ks < 2; ++ks) {
      const int ob = ks * 64 + g * 16;
      short8 af[4], bfr[4];
      #pragma unroll
      for (int m = 0; m < 4; ++m) {
        const int row = wr + m * 16 + lr;
        af[m] = *reinterpret_cast<const short8*>(Ab + row * 128 + (ob ^ swz128(row)));
      }
      #pragma unroll
      for (int n = 0; n < 4; ++n) {
        const int row = wc + n * 16 + lr;
        bfr[n] = *reinterpret_cast<const short8*>(Bb + row * 128 + (ob ^ swz128(row)));
      }
      mm4x4(af, bfr, acc);
    }
    if (t < 3) {
      asm volatile("s_waitcnt vmcnt(0)" ::: "memory");
      __builtin_amdgcn_s_barrier();
    }
  }
  __syncthreads();   // all LDS reads done -> staging buffers reusable for Lba
  // Lba: [128 b-cols][136 pad] u16 (34,816 B). 272 B rows: 16B-aligned, 2-way
  // bank aliasing on both the scattered writes and the row-reads (free).
  u16 (*Lba)[136] = reinterpret_cast<u16 (*)[136]>(smem);

  float nbv[4], nav[4][4];
  #pragma unroll
  for (int n = 0; n < 4; ++n) nbv[n] = nb[bn + wc + n * 16 + lr];
  #pragma unroll
  for (int m = 0; m < 4; ++m) {
    const int rowb = bm + wr + m * 16 + g * 4;
    #pragma unroll
    for (int r = 0; r < 4; ++r) nav[m][r] = na[rowb + r];
  }

  float rowsum[4][4] = {}, colsum[4] = {};
  #pragma unroll
  for (int m = 0; m < 4; ++m) {
    const int rowb = bm + wr + m * 16 + g * 4;        // global a-row base
    const int ilb = wr + m * 16 + g * 4;              // local a-row base
    #pragma unroll
    for (int n = 0; n < 4; ++n) {
      const int col = bn + wc + n * 16 + lr;          // global b-col
      const int jl = wc + n * 16 + lr;                // local b-col
      #pragma unroll
      for (int r = 0; r < 4; ++r) {
        const float s2 = 2.f * acc[m][n][r];
        const float w0 = __expf((s2 - nbv[n]) * SCALE);       // dir ab
        Eab[(size_t)(rowb + r) * NTOT + col] = f2bf(w0);
        rowsum[m][r] += w0;
        const float w1 = __expf((s2 - nav[m][r]) * SCALE);    // dir ba
        colsum[n] += w1;
        Lba[jl][ilb + r] = f2bf(w1);
      }
    }
  }
  // ab row sums -> dnp0 (layout identical to previous rounds)
  #pragma unroll
  for (int m = 0; m < 4; ++m) {
    const int rowb = bm + wr + m * 16 + g * 4;
    #pragma unroll
    for (int r = 0; r < 4; ++r) {
      float s = rowsum[m][r];
      #pragma unroll
      for (int o = 1; o < 16; o <<= 1) s += __shfl_xor(s, o, 64);
      if (lr == 0) dnp0[(size_t)(rowb + r) * 64 + bx * 2 + (wid & 1)] = s;
    }
  }
  // ba row sums (= tile col sums): reduce over g-groups (lanes ^16, ^32)
  #pragma unroll
  for (int n = 0; n < 4; ++n) {
    float v = colsum[n];
    v += __shfl_xor(v, 16, 64);
    v += __shfl_xor(v, 32, 64);
    if (g == 0)
      dnp1[(size_t)(bn + wc + n * 16 + lr) * 64 + by * 2 + (wid >> 1)] = v;
  }
  __syncthreads();
  // coalesced E_ba write-out: 16 threads per b-row, 256 B contiguous per row
  #pragma unroll
  for (int p = 0; p < 8; ++p) {
    const int jl = (tid >> 4) + p * 16;
    const int il = (tid & 15) * 8;
    const short8 v = *reinterpret_cast<const short8*>(&Lba[jl][il]);
    *reinterpret_cast<short8*>(&Eba[(size_t)(bn + jl) * NTOT + bm + il]) = v;
  }
}

// ---------------------------------------------------------------------------
// Qp = E . Yt^T, split-K 4, both dirs (round-10 structure, XCD-pinned dk).
__global__ __launch_bounds__(256, 2) void gemm_qp_k(const u16* __restrict__ E,
                                                    const u16* __restrict__ att,
                                                    const u16* __restrict__ btt,
                                                    float* __restrict__ Qp) {
  const int wg = blockIdx.x;
  const int dk = wg & 7;
  const int j = wg >> 3;
  const int dir = dk >> 2, kz = dk & 3;
  const int bxi = j & 1, byi = j >> 1;

  const u16* __restrict__ A = E + (size_t)dir * NTOT * NTOT;
  const u16* __restrict__ B = dir ? att : btt;
  float* __restrict__ C = Qp + (size_t)dir * 4 * NTOT * CH + (size_t)kz * NTOT * CH;
  const int k0base = kz * (NTOT / 4);

  __shared__ u16 As[2][128][64];
  __shared__ u16 Bs[2][128][64];
  const int tid = threadIdx.x, wid = tid >> 6, lane = tid & 63;
  const int bn = bxi * 128, bm = byi * 128;
  const int wr = (wid >> 1) * 64, wc = (wid & 1) * 64;
  const int lr = lane & 15;

  auto stage = [&](int t, int bi) {
    const int k0 = k0base + t * 64;
    #pragma unroll
    for (int i = 0; i < 4; ++i) {
      const int lb = (wid + 4 * i) * 1024;
      const int db = lb + lane * 16;
      const int r = db >> 7;
      const int cb = (db & 127) ^ swz128(r);
      gload_lds(A + (size_t)(bm + r) * NTOT + k0 + (cb >> 1), (char*)&As[bi][0][0] + lb);
      gload_lds(B + (size_t)(bn + r) * NTOT + k0 + (cb >> 1), (char*)&Bs[bi][0][0] + lb);
    }
  };

  floatx4 acc[4][4] = {};
  stage(0, 0);
  asm volatile("s_waitcnt vmcnt(0)" ::: "memory");
  __builtin_amdgcn_s_barrier();
  for (int t = 0; t < 16; ++t) {
    if (t < 15) stage(t + 1, (t + 1) & 1);
    const int bi = t & 1;
    const char* Ab = (const char*)&As[bi][0][0];
    const char* Bb = (const char*)&Bs[bi][0][0];
    #pragma unroll
    for (int ks = 0; ks < 2; ++ks) {
      const int ob = ks * 64 + (lane >> 4) * 16;
      short8 af[4], bfr[4];
      #pragma unroll
      for (int m = 0; m < 4; ++m) {
        const int row = wr + m * 16 + lr;
        af[m] = *reinterpret_cast<const short8*>(Ab + row * 128 + (ob ^ swz128(row)));
      }
      #pragma unroll
      for (int n = 0; n < 4; ++n) {
        const int row = wc + n * 16 + lr;
        bfr[n] = *reinterpret_cast<const short8*>(Bb + row * 128 + (ob ^ swz128(row)));
      }
      mm4x4(af, bfr, acc);
    }
    asm volatile("s_waitcnt vmcnt(0)" ::: "memory");
    __builtin_amdgcn_s_barrier();
  }
  #pragma unroll
  for (int m = 0; m < 4; ++m) {
    const int row = bm + wr + m * 16 + (lane >> 4) * 4;
    #pragma unroll
    for (int n = 0; n < 4; ++n) {
      const int col = bn + wc + n * 16 + lr;
      #pragma unroll
      for (int r = 0; r < 4; ++r)
        C[(size_t)(row + r) * CH + col] = acc[m][n][r];
    }
  }
}

// Q = (sum of 4 split-K partials) / dn -> bf16. Block per row; both dirs via z.
__global__ __launch_bounds__(256) void reduce_q_k(const float* __restrict__ Qp,
                                                  const float* __restrict__ dnp,
                                                  u16* __restrict__ Qb) {
  const int dir = blockIdx.z;
  Qp += (size_t)dir * 4 * NTOT * CH;
  dnp += (size_t)dir * NTOT * 64;
  Qb += (size_t)dir * NTOT * CH;
  const int row = blockIdx.x, tid = threadIdx.x;
  __shared__ float sdn;
  if (tid < 64) {
    float s = dnp[(size_t)row * 64 + tid];
    s = wave_sum64(s);
    if (tid == 0) sdn = 1.0f / s;
  }
  __syncthreads();
  const float rdn = sdn;
  const size_t o = (size_t)row * CH + tid;
  const size_t st = (size_t)NTOT * CH;
  const float q = (Qp[o] + Qp[o + st] + Qp[o + 2 * st] + Qp[o + 3 * st]) * rdn;
  Qb[o] = f2bf(q);
}

// ---------------------------------------------------------------------------
// Phase-2 flash (round-10 structure): T-tile = Qb . X^T never materialized;
// w = exp((2T-nx)*SCALE); s0, s1 = sum w*(idx-c), s2 = sum w*(idx-c)^2 per row.
// XCD-affinity linear grid.
__global__ __launch_bounds__(256, 2) void flash_stats_k(const u16* __restrict__ Qball,
                                                        const u16* __restrict__ abf,
                                                        const u16* __restrict__ bbf,
                                                        const float* __restrict__ na,
                                                        const float* __restrict__ nb,
                                                        const float* __restrict__ idxa,
                                                        const float* __restrict__ idxb,
                                                        float4* __restrict__ statsp) {
  const int wg = blockIdx.x;
  const int dir = wg >> 9;                  // 512 blocks per dir
  const int w = wg & 511;
  const int xcd = w & 7;
  const int local = w >> 3;                 // [0,64)
  const int bx = local & 15;                // j-chunk [0,16)
  const int by = xcd * 4 + (local >> 4);    // bm [0,32): 4 consecutive per XCD

  const u16* __restrict__ Qb = Qball + (size_t)dir * NTOT * CH;
  const u16* __restrict__ X = dir ? bbf : abf;
  const float* __restrict__ nx = dir ? nb : na;
  const float* __restrict__ idx = dir ? idxb : idxa;
  statsp += (size_t)dir * NTOT * 32;

  __shared__ u16 As[2][128][64];
  __shared__ u16 Bs[2][128][64];
  const int tid = threadIdx.x, wid = tid >> 6, lane = tid & 63;
  const int bm = by * 128;
  const int jbase = bx * 256;
  const int wr = (wid >> 1) * 64, wc = (wid & 1) * 64;
  const int lr = lane & 15;

  auto stage = [&](int t, int bi) {
    const int k0 = (t & 3) * 64;
    const int bn = jbase + (t >> 2) * 128;
    #pragma unroll
    for (int i = 0; i < 4; ++i) {
      const int lb = (wid + 4 * i) * 1024;
      const int db = lb + lane * 16;
      const int r = db >> 7;
      const int cb = (db & 127) ^ swz128(r);
      gload_lds(Qb + (size_t)(bm + r) * CH + k0 + (cb >> 1), (char*)&As[bi][0][0] + lb);
      gload_lds(X + (size_t)(bn + r) * CH + k0 + (cb >> 1), (char*)&Bs[bi][0][0] + lb);
    }
  };

  float cen[4][4];
  #pragma unroll
  for (int m = 0; m < 4; ++m) {
    const int rowb = bm + wr + m * 16 + (lane >> 4) * 4;
    #pragma unroll
    for (int r = 0; r < 4; ++r) cen[m][r] = idx[rowb + r];
  }
  float s0[4][4] = {}, s1[4][4] = {}, s2[4][4] = {};
  floatx4 acc[4][4] = {};

  stage(0, 0);
  asm volatile("s_waitcnt vmcnt(0)" ::: "memory");
  __builtin_amdgcn_s_barrier();
  #pragma unroll
  for (int t = 0; t < 8; ++t) {
    if (t < 7) stage(t + 1, (t + 1) & 1);
    const int bi = t & 1;
    const char* Ab = (const char*)&As[bi][0][0];
    const char* Bb = (const char*)&Bs[bi][0][0];
    #pragma unroll
    for (int ks = 0; ks < 2; ++ks) {
      const int ob = ks * 64 + (lane >> 4) * 16;
      short8 af[4], bfr[4];
      #pragma unroll
      for (int m = 0; m < 4; ++m) {
        const int row = wr + m * 16 + lr;
        af[m] = *reinterpret_cast<const short8*>(Ab + row * 128 + (ob ^ swz128(row)));
      }
      #pragma unroll
      for (int n = 0; n < 4; ++n) {
        const int row = wc + n * 16 + lr;
        bfr[n] = *reinterpret_cast<const short8*>(Bb + row * 128 + (ob ^ swz128(row)));
      }
      mm4x4(af, bfr, acc);
    }
    if ((t & 3) == 3) {  // end of a j-tile: fold stats, reset acc
      const int bn = jbase + (t >> 2) * 128;
      #pragma unroll
      for (int n = 0; n < 4; ++n) {
        const int col = bn + wc + n * 16 + lr;
        const float nxv = nx[col];
        const float iv = idx[col];
        #pragma unroll
        for (int m = 0; m < 4; ++m) {
          #pragma unroll
          for (int r = 0; r < 4; ++r) {
            const float w2 = __expf((2.f * acc[m][n][r] - nxv) * SCALE);
            const float d = iv - cen[m][r];
            s0[m][r] += w2;
            s1[m][r] += w2 * d;
            s2[m][r] += w2 * d * d;
            acc[m][n][r] = 0.f;
          }
        }
      }
    }
    if (t < 7) {
      asm volatile("s_waitcnt vmcnt(0)" ::: "memory");
      __builtin_amdgcn_s_barrier();
    }
  }
  #pragma unroll
  for (int m = 0; m < 4; ++m) {
    const int rowb = bm + wr + m * 16 + (lane >> 4) * 4;
    #pragma unroll
    for (int r = 0; r < 4; ++r) {
      float a = s0[m][r], b = s1[m][r], c = s2[m][r];
      #pragma unroll
      for (int o = 1; o < 16; o <<= 1) {
        a += __shfl_xor(a, o, 64);
        b += __shfl_xor(b, o, 64);
        c += __shfl_xor(c, o, 64);
      }
      if (lr == 0)
        statsp[(size_t)(rowb + r) * 32 + bx * 2 + (wid & 1)] = make_float4(a, b, c, 0.f);
    }
  }
}

// per-row: combine 32 partials -> loss term. mu = S1/S0; var = S2/S0 - mu^2.
__global__ __launch_bounds__(256) void stats_combine_k(const float4* __restrict__ statsp,
                                                       float* __restrict__ terms) {
  const int row = blockIdx.x * 256 + threadIdx.x;   // 0..2*NTOT-1
  float S0 = 0.f, S1 = 0.f, S2 = 0.f;
  #pragma unroll
  for (int p = 0; p < 32; ++p) {
    const float4 v = statsp[(size_t)row * 32 + p];
    S0 += v.x; S1 += v.y; S2 += v.z;
  }
  const float mu = S1 / S0;
  const float var = S2 / S0 - mu * mu;
  terms[row] = mu * mu / var + LAM * logf(var);
}

__global__ __launch_bounds__(256) void final_reduce_k(const float* __restrict__ terms,
                                                      float* __restrict__ out) {
  float s = 0.f;
  for (int i = threadIdx.x; i < 2 * NTOT; i += 256) s += terms[i];
  __shared__ float red[4];
  s = wave_sum64(s);
  if ((threadIdx.x & 63) == 0) red[threadIdx.x >> 6] = s;
  __syncthreads();
  if (threadIdx.x == 0) out[0] = (red[0] + red[1] + red[2] + red[3]) * (1.0f / (2.0f * NTOT));
}

extern "C" void kernel_launch(void* const* d_in, const int* in_sizes, int n_in,
                              void* d_out, int out_size, void* d_ws, size_t ws_size,
                              hipStream_t stream) {
  const float* a    = (const float*)d_in[0];
  const float* b    = (const float*)d_in[1];
  const float* idxa = (const float*)d_in[2];
  const float* idxb = (const float*)d_in[3];
  float* out = (float*)d_out;
  char* ws = (char*)d_ws;

  size_t off = 0;
  u16*    E    = (u16*)(ws + off);    off += 2 * (size_t)NTOT * NTOT * 2;   // 64 MB
  float*  Qp   = (float*)(ws + off);  off += 2 * 4 * (size_t)NTOT * CH * 4; // 32 MB
  u16*    Qb   = (u16*)(ws + off);    off += 2 * (size_t)NTOT * CH * 2;     // 4 MB
  u16*    abf  = (u16*)(ws + off);    off += (size_t)NTOT * CH * 2;
  u16*    bbf  = (u16*)(ws + off);    off += (size_t)NTOT * CH * 2;
  u16*    att  = (u16*)(ws + off);    off += (size_t)NTOT * CH * 2;
  u16*    btt  = (u16*)(ws + off);    off += (size_t)NTOT * CH * 2;
  float*  na   = (float*)(ws + off);  off += (size_t)NTOT * 4;
  float*  nb   = (float*)(ws + off);  off += (size_t)NTOT * 4;
  float*  dnp  = (float*)(ws + off);  off += 2 * (size_t)NTOT * 64 * 4;     // 2 MB
  float4* stp  = (float4*)(ws + off); off += 2 * (size_t)NTOT * 32 * 16;    // 4 MB
  float*  terms = (float*)(ws + off);

  cvt_norm_k<<<2 * NTOT, 64, 0, stream>>>(a, b, abf, bbf, na, nb);
  transpose2_k<<<dim3(CH / 32, NTOT / 32, 2), 256, 0, stream>>>(abf, bbf, att, btt);
  gemm_exp_k<<<dim3(32, 32), 256, 0, stream>>>(abf, bbf, na, nb, E, dnp);
  gemm_qp_k<<<512, 256, 0, stream>>>(E, att, btt, Qp);
  reduce_q_k<<<dim3(NTOT, 1, 2), 256, 0, stream>>>(Qp, dnp, Qb);
  flash_stats_k<<<1024, 256, 0, stream>>>(Qb, abf, bbf, na, nb, idxa, idxb, stp);
  stats_combine_k<<<2 * NTOT / 256, 256, 0, stream>>>(stp, terms);
  final_reduce_k<<<1, 256, 0, stream>>>(terms, out);
}

// Round 14
// 124.743 us; speedup vs baseline: 1.1269x; 1.0024x over previous
//
#include <hip/hip_runtime.h>

#define NTOT 4096
#define CH 256
#define SCALE 0.0390625f   // 1/(256*0.1)
#define LAM 0.001f

typedef unsigned short u16;
typedef __attribute__((ext_vector_type(8))) short short8;   // 8 bf16 (4 VGPRs)
typedef __attribute__((ext_vector_type(4))) float floatx4;  // MFMA acc

__device__ __forceinline__ float wave_sum64(float v) {
  #pragma unroll
  for (int o = 32; o; o >>= 1) v += __shfl_down(v, o, 64);
  return v;
}
__device__ __forceinline__ u16 f2bf(float f) {  // round-to-nearest-even
  unsigned u = __float_as_uint(f);
  u += 0x7fffu + ((u >> 16) & 1u);
  return (u16)(u >> 16);
}
__device__ __forceinline__ float bf2f(u16 h) {
  return __uint_as_float(((unsigned)h) << 16);
}
__device__ __forceinline__ void gload_lds(const u16* g, void* l) {
  __builtin_amdgcn_global_load_lds((const __attribute__((address_space(1))) void*)g,
                                   (__attribute__((address_space(3))) void*)l, 16, 0, 0);
}
__device__ __forceinline__ void mm4x4(const short8 (&av)[4], const short8 (&bv)[4],
                                      floatx4 (&acc)[4][4]) {
  #pragma unroll
  for (int m = 0; m < 4; ++m)
    #pragma unroll
    for (int n = 0; n < 4; ++n)
      acc[m][n] = __builtin_amdgcn_mfma_f32_16x16x32_bf16(av[m], bv[n], acc[m][n], 0, 0, 0);
}
// 128 B LDS rows: byte ^= (row&7)<<4 (verified rounds 6-13, conflicts -> 0)
__device__ __forceinline__ int swz128(int row) { return (row & 7) << 4; }

// f32 -> bf16 for both inputs + row norms of the ROUNDED values (one wave/row).
__global__ __launch_bounds__(64) void cvt_norm_k(const float* __restrict__ a,
                                                 const float* __restrict__ b,
                                                 u16* __restrict__ ab, u16* __restrict__ bb,
                                                 float* __restrict__ na, float* __restrict__ nb) {
  int row = blockIdx.x;
  const float* src; u16* dst; float* nd;
  if (row < NTOT) { src = a; dst = ab; nd = na; }
  else { row -= NTOT; src = b; dst = bb; nd = nb; }
  const float4 v = *reinterpret_cast<const float4*>(src + (size_t)row * CH + threadIdx.x * 4);
  const u16 h0 = f2bf(v.x), h1 = f2bf(v.y), h2 = f2bf(v.z), h3 = f2bf(v.w);
  uint2 st;
  st.x = (unsigned)h0 | ((unsigned)h1 << 16);
  st.y = (unsigned)h2 | ((unsigned)h3 << 16);
  *reinterpret_cast<uint2*>(dst + (size_t)row * CH + threadIdx.x * 4) = st;
  const float f0 = bf2f(h0), f1 = bf2f(h1), f2 = bf2f(h2), f3 = bf2f(h3);
  float s = f0 * f0 + f1 * f1 + f2 * f2 + f3 * f3;
  s = wave_sum64(s);
  if (threadIdx.x == 0) nd[row] = s;
}

// [4096][256] -> [256][4096] bf16 transpose for both inputs (z selects a/b)
__global__ __launch_bounds__(256) void transpose2_k(const u16* __restrict__ ab,
                                                    const u16* __restrict__ bb,
                                                    u16* __restrict__ at, u16* __restrict__ bt) {
  const u16* __restrict__ src = blockIdx.z ? bb : ab;
  u16* __restrict__ dst = blockIdx.z ? bt : at;
  __shared__ u16 t[32][33];
  const int bx = blockIdx.x * 32, by = blockIdx.y * 32;
  const int lx = threadIdx.x & 31, ly = threadIdx.x >> 5;
  #pragma unroll
  for (int i = 0; i < 32; i += 8)
    t[ly + i][lx] = src[(size_t)(by + ly + i) * CH + bx + lx];
  __syncthreads();
  #pragma unroll
  for (int i = 0; i < 32; i += 8)
    dst[(size_t)(bx + ly + i) * NTOT + by + lx] = t[lx][ly + i];
}

// ---------------------------------------------------------------------------
// SHARED-S phase-1 (round-13 verified). NEW: narrow-slice XCD residency.
// Linear grid 1024; xcd = wg%8 owns bx in {xcd*4..xcd*4+3} (512 b-cols =
// 256 KB, L2-resident with margin) x ALL by (a streams through once).
__global__ __launch_bounds__(256, 2) void gemm_exp_k(const u16* __restrict__ abf,
                                                     const u16* __restrict__ bbf,
                                                     const float* __restrict__ na,
                                                     const float* __restrict__ nb,
                                                     u16* __restrict__ E,
                                                     float* __restrict__ dnp) {
  const int wg = blockIdx.x;
  const int xcd = wg & 7;
  const int local = wg >> 3;                // [0,128)
  const int bx = xcd * 4 + (local & 3);     // b-col tile: 4 per XCD (256 KB)
  const int by = local >> 2;                // a-row tile [0,32): streams
  const int bn = bx * 128, bm = by * 128;
  u16* __restrict__ Eab = E;                                // [a-row][b-col]
  u16* __restrict__ Eba = E + (size_t)NTOT * NTOT;          // [b-row][a-col]
  float* __restrict__ dnp0 = dnp;                           // ab row sums
  float* __restrict__ dnp1 = dnp + (size_t)NTOT * 64;       // ba row sums

  __shared__ u16 smem[32768];   // 64 KB: As dbuf [0,32KB), Bs dbuf [32KB,64KB)
  const int tid = threadIdx.x, wid = tid >> 6, lane = tid & 63;
  const int wr = (wid >> 1) * 64, wc = (wid & 1) * 64;
  const int lr = lane & 15, g = lane >> 4;

  auto stage = [&](int t, int bi) {
    const int k0 = t * 64;
    #pragma unroll
    for (int i = 0; i < 4; ++i) {
      const int lb = (wid + 4 * i) * 1024;          // wave-uniform LDS byte base
      const int db = lb + lane * 16;                // lane's linear dest byte
      const int r = db >> 7;                        // dest row (128 B rows)
      const int cb = (db & 127) ^ swz128(r);        // inverse-swizzled source col
      gload_lds(abf + (size_t)(bm + r) * CH + k0 + (cb >> 1), (char*)smem + bi * 16384 + lb);
      gload_lds(bbf + (size_t)(bn + r) * CH + k0 + (cb >> 1), (char*)smem + 32768 + bi * 16384 + lb);
    }
  };

  floatx4 acc[4][4] = {};
  stage(0, 0);
  asm volatile("s_waitcnt vmcnt(0)" ::: "memory");
  __builtin_amdgcn_s_barrier();
  #pragma unroll
  for (int t = 0; t < 4; ++t) {
    if (t < 3) stage(t + 1, (t + 1) & 1);
    const int bi = t & 1;
    const char* Ab = (const char*)smem + bi * 16384;
    const char* Bb = (const char*)smem + 32768 + bi * 16384;
    #pragma unroll
    for (int ks = 0; ks < 2; ++ks) {
      const int ob = ks * 64 + g * 16;
      short8 af[4], bfr[4];
      #pragma unroll
      for (int m = 0; m < 4; ++m) {
        const int row = wr + m * 16 + lr;
        af[m] = *reinterpret_cast<const short8*>(Ab + row * 128 + (ob ^ swz128(row)));
      }
      #pragma unroll
      for (int n = 0; n < 4; ++n) {
        const int row = wc + n * 16 + lr;
        bfr[n] = *reinterpret_cast<const short8*>(Bb + row * 128 + (ob ^ swz128(row)));
      }
      mm4x4(af, bfr, acc);
    }
    if (t < 3) {
      asm volatile("s_waitcnt vmcnt(0)" ::: "memory");
      __builtin_amdgcn_s_barrier();
    }
  }
  __syncthreads();   // all LDS reads done -> staging buffers reusable for Lba
  // Lba: [128 b-cols][136 pad] u16 (34,816 B). 2-way bank aliasing (free).
  u16 (*Lba)[136] = reinterpret_cast<u16 (*)[136]>(smem);

  float nbv[4], nav[4][4];
  #pragma unroll
  for (int n = 0; n < 4; ++n) nbv[n] = nb[bn + wc + n * 16 + lr];
  #pragma unroll
  for (int m = 0; m < 4; ++m) {
    const int rowb = bm + wr + m * 16 + g * 4;
    #pragma unroll
    for (int r = 0; r < 4; ++r) nav[m][r] = na[rowb + r];
  }

  float rowsum[4][4] = {}, colsum[4] = {};
  #pragma unroll
  for (int m = 0; m < 4; ++m) {
    const int rowb = bm + wr + m * 16 + g * 4;        // global a-row base
    const int ilb = wr + m * 16 + g * 4;              // local a-row base
    #pragma unroll
    for (int n = 0; n < 4; ++n) {
      const int col = bn + wc + n * 16 + lr;          // global b-col
      const int jl = wc + n * 16 + lr;                // local b-col
      #pragma unroll
      for (int r = 0; r < 4; ++r) {
        const float s2 = 2.f * acc[m][n][r];
        const float w0 = __expf((s2 - nbv[n]) * SCALE);       // dir ab
        Eab[(size_t)(rowb + r) * NTOT + col] = f2bf(w0);
        rowsum[m][r] += w0;
        const float w1 = __expf((s2 - nav[m][r]) * SCALE);    // dir ba
        colsum[n] += w1;
        Lba[jl][ilb + r] = f2bf(w1);
      }
    }
  }
  // ab row sums -> dnp0 (layout unchanged)
  #pragma unroll
  for (int m = 0; m < 4; ++m) {
    const int rowb = bm + wr + m * 16 + g * 4;
    #pragma unroll
    for (int r = 0; r < 4; ++r) {
      float s = rowsum[m][r];
      #pragma unroll
      for (int o = 1; o < 16; o <<= 1) s += __shfl_xor(s, o, 64);
      if (lr == 0) dnp0[(size_t)(rowb + r) * 64 + bx * 2 + (wid & 1)] = s;
    }
  }
  // ba row sums (= tile col sums): reduce over g-groups (lanes ^16, ^32)
  #pragma unroll
  for (int n = 0; n < 4; ++n) {
    float v = colsum[n];
    v += __shfl_xor(v, 16, 64);
    v += __shfl_xor(v, 32, 64);
    if (g == 0)
      dnp1[(size_t)(bn + wc + n * 16 + lr) * 64 + by * 2 + (wid >> 1)] = v;
  }
  __syncthreads();
  // coalesced E_ba write-out: 16 threads per b-row, 256 B contiguous per row
  #pragma unroll
  for (int p = 0; p < 8; ++p) {
    const int jl = (tid >> 4) + p * 16;
    const int il = (tid & 15) * 8;
    const short8 v = *reinterpret_cast<const short8*>(&Lba[jl][il]);
    *reinterpret_cast<short8*>(&Eba[(size_t)(bn + jl) * NTOT + bm + il]) = v;
  }
}

// ---------------------------------------------------------------------------
// Qp = E . Yt^T, split-K 4, both dirs (round-10 structure, XCD-pinned dk).
__global__ __launch_bounds__(256, 2) void gemm_qp_k(const u16* __restrict__ E,
                                                    const u16* __restrict__ att,
                                                    const u16* __restrict__ btt,
                                                    float* __restrict__ Qp) {
  const int wg = blockIdx.x;
  const int dk = wg & 7;
  const int j = wg >> 3;
  const int dir = dk >> 2, kz = dk & 3;
  const int bxi = j & 1, byi = j >> 1;

  const u16* __restrict__ A = E + (size_t)dir * NTOT * NTOT;
  const u16* __restrict__ B = dir ? att : btt;
  float* __restrict__ C = Qp + (size_t)dir * 4 * NTOT * CH + (size_t)kz * NTOT * CH;
  const int k0base = kz * (NTOT / 4);

  __shared__ u16 As[2][128][64];
  __shared__ u16 Bs[2][128][64];
  const int tid = threadIdx.x, wid = tid >> 6, lane = tid & 63;
  const int bn = bxi * 128, bm = byi * 128;
  const int wr = (wid >> 1) * 64, wc = (wid & 1) * 64;
  const int lr = lane & 15;

  auto stage = [&](int t, int bi) {
    const int k0 = k0base + t * 64;
    #pragma unroll
    for (int i = 0; i < 4; ++i) {
      const int lb = (wid + 4 * i) * 1024;
      const int db = lb + lane * 16;
      const int r = db >> 7;
      const int cb = (db & 127) ^ swz128(r);
      gload_lds(A + (size_t)(bm + r) * NTOT + k0 + (cb >> 1), (char*)&As[bi][0][0] + lb);
      gload_lds(B + (size_t)(bn + r) * NTOT + k0 + (cb >> 1), (char*)&Bs[bi][0][0] + lb);
    }
  };

  floatx4 acc[4][4] = {};
  stage(0, 0);
  asm volatile("s_waitcnt vmcnt(0)" ::: "memory");
  __builtin_amdgcn_s_barrier();
  for (int t = 0; t < 16; ++t) {
    if (t < 15) stage(t + 1, (t + 1) & 1);
    const int bi = t & 1;
    const char* Ab = (const char*)&As[bi][0][0];
    const char* Bb = (const char*)&Bs[bi][0][0];
    #pragma unroll
    for (int ks = 0; ks < 2; ++ks) {
      const int ob = ks * 64 + (lane >> 4) * 16;
      short8 af[4], bfr[4];
      #pragma unroll
      for (int m = 0; m < 4; ++m) {
        const int row = wr + m * 16 + lr;
        af[m] = *reinterpret_cast<const short8*>(Ab + row * 128 + (ob ^ swz128(row)));
      }
      #pragma unroll
      for (int n = 0; n < 4; ++n) {
        const int row = wc + n * 16 + lr;
        bfr[n] = *reinterpret_cast<const short8*>(Bb + row * 128 + (ob ^ swz128(row)));
      }
      mm4x4(af, bfr, acc);
    }
    asm volatile("s_waitcnt vmcnt(0)" ::: "memory");
    __builtin_amdgcn_s_barrier();
  }
  #pragma unroll
  for (int m = 0; m < 4; ++m) {
    const int row = bm + wr + m * 16 + (lane >> 4) * 4;
    #pragma unroll
    for (int n = 0; n < 4; ++n) {
      const int col = bn + wc + n * 16 + lr;
      #pragma unroll
      for (int r = 0; r < 4; ++r)
        C[(size_t)(row + r) * CH + col] = acc[m][n][r];
    }
  }
}

// Q = (sum of 4 split-K partials) / dn -> bf16. Block per row; both dirs via z.
__global__ __launch_bounds__(256) void reduce_q_k(const float* __restrict__ Qp,
                                                  const float* __restrict__ dnp,
                                                  u16* __restrict__ Qb) {
  const int dir = blockIdx.z;
  Qp += (size_t)dir * 4 * NTOT * CH;
  dnp += (size_t)dir * NTOT * 64;
  Qb += (size_t)dir * NTOT * CH;
  const int row = blockIdx.x, tid = threadIdx.x;
  __shared__ float sdn;
  if (tid < 64) {
    float s = dnp[(size_t)row * 64 + tid];
    s = wave_sum64(s);
    if (tid == 0) sdn = 1.0f / s;
  }
  __syncthreads();
  const float rdn = sdn;
  const size_t o = (size_t)row * CH + tid;
  const size_t st = (size_t)NTOT * CH;
  const float q = (Qp[o] + Qp[o + st] + Qp[o + 2 * st] + Qp[o + 3 * st]) * rdn;
  Qb[o] = f2bf(q);
}

// ---------------------------------------------------------------------------
// Phase-2 flash (round-13 verified). NEW: narrow-slice XCD residency.
// xcd = wg%8 owns j-chunks {xcd*2, xcd*2+1} (512 X-rows = 256 KB per dir,
// L2-resident) x ALL bm (Qb streams through once).
__global__ __launch_bounds__(256, 2) void flash_stats_k(const u16* __restrict__ Qball,
                                                        const u16* __restrict__ abf,
                                                        const u16* __restrict__ bbf,
                                                        const float* __restrict__ na,
                                                        const float* __restrict__ nb,
                                                        const float* __restrict__ idxa,
                                                        const float* __restrict__ idxb,
                                                        float4* __restrict__ statsp) {
  const int wg = blockIdx.x;
  const int dir = wg >> 9;                  // 512 blocks per dir
  const int w = wg & 511;
  const int xcd = w & 7;
  const int local = w >> 3;                 // [0,64)
  const int bx = xcd * 2 + (local & 1);     // j-chunk: 2 per XCD (256 KB)
  const int by = local >> 1;                // bm [0,32): streams

  const u16* __restrict__ Qb = Qball + (size_t)dir * NTOT * CH;
  const u16* __restrict__ X = dir ? bbf : abf;
  const float* __restrict__ nx = dir ? nb : na;
  const float* __restrict__ idx = dir ? idxb : idxa;
  statsp += (size_t)dir * NTOT * 32;

  __shared__ u16 As[2][128][64];
  __shared__ u16 Bs[2][128][64];
  const int tid = threadIdx.x, wid = tid >> 6, lane = tid & 63;
  const int bm = by * 128;
  const int jbase = bx * 256;
  const int wr = (wid >> 1) * 64, wc = (wid & 1) * 64;
  const int lr = lane & 15;

  auto stage = [&](int t, int bi) {
    const int k0 = (t & 3) * 64;
    const int bn = jbase + (t >> 2) * 128;
    #pragma unroll
    for (int i = 0; i < 4; ++i) {
      const int lb = (wid + 4 * i) * 1024;
      const int db = lb + lane * 16;
      const int r = db >> 7;
      const int cb = (db & 127) ^ swz128(r);
      gload_lds(Qb + (size_t)(bm + r) * CH + k0 + (cb >> 1), (char*)&As[bi][0][0] + lb);
      gload_lds(X + (size_t)(bn + r) * CH + k0 + (cb >> 1), (char*)&Bs[bi][0][0] + lb);
    }
  };

  float cen[4][4];
  #pragma unroll
  for (int m = 0; m < 4; ++m) {
    const int rowb = bm + wr + m * 16 + (lane >> 4) * 4;
    #pragma unroll
    for (int r = 0; r < 4; ++r) cen[m][r] = idx[rowb + r];
  }
  float s0[4][4] = {}, s1[4][4] = {}, s2[4][4] = {};
  floatx4 acc[4][4] = {};

  stage(0, 0);
  asm volatile("s_waitcnt vmcnt(0)" ::: "memory");
  __builtin_amdgcn_s_barrier();
  #pragma unroll
  for (int t = 0; t < 8; ++t) {
    if (t < 7) stage(t + 1, (t + 1) & 1);
    const int bi = t & 1;
    const char* Ab = (const char*)&As[bi][0][0];
    const char* Bb = (const char*)&Bs[bi][0][0];
    #pragma unroll
    for (int ks = 0; ks < 2; ++ks) {
      const int ob = ks * 64 + (lane >> 4) * 16;
      short8 af[4], bfr[4];
      #pragma unroll
      for (int m = 0; m < 4; ++m) {
        const int row = wr + m * 16 + lr;
        af[m] = *reinterpret_cast<const short8*>(Ab + row * 128 + (ob ^ swz128(row)));
      }
      #pragma unroll
      for (int n = 0; n < 4; ++n) {
        const int row = wc + n * 16 + lr;
        bfr[n] = *reinterpret_cast<const short8*>(Bb + row * 128 + (ob ^ swz128(row)));
      }
      mm4x4(af, bfr, acc);
    }
    if ((t & 3) == 3) {  // end of a j-tile: fold stats, reset acc
      const int bn = jbase + (t >> 2) * 128;
      #pragma unroll
      for (int n = 0; n < 4; ++n) {
        const int col = bn + wc + n * 16 + lr;
        const float nxv = nx[col];
        const float iv = idx[col];
        #pragma unroll
        for (int m = 0; m < 4; ++m) {
          #pragma unroll
          for (int r = 0; r < 4; ++r) {
            const float w2 = __expf((2.f * acc[m][n][r] - nxv) * SCALE);
            const float d = iv - cen[m][r];
            s0[m][r] += w2;
            s1[m][r] += w2 * d;
            s2[m][r] += w2 * d * d;
            acc[m][n][r] = 0.f;
          }
        }
      }
    }
    if (t < 7) {
      asm volatile("s_waitcnt vmcnt(0)" ::: "memory");
      __builtin_amdgcn_s_barrier();
    }
  }
  #pragma unroll
  for (int m = 0; m < 4; ++m) {
    const int rowb = bm + wr + m * 16 + (lane >> 4) * 4;
    #pragma unroll
    for (int r = 0; r < 4; ++r) {
      float a = s0[m][r], b = s1[m][r], c = s2[m][r];
      #pragma unroll
      for (int o = 1; o < 16; o <<= 1) {
        a += __shfl_xor(a, o, 64);
        b += __shfl_xor(b, o, 64);
        c += __shfl_xor(c, o, 64);
      }
      if (lr == 0)
        statsp[(size_t)(rowb + r) * 32 + bx * 2 + (wid & 1)] = make_float4(a, b, c, 0.f);
    }
  }
}

// per-row: combine 32 partials -> loss term. mu = S1/S0; var = S2/S0 - mu^2.
__global__ __launch_bounds__(256) void stats_combine_k(const float4* __restrict__ statsp,
                                                       float* __restrict__ terms) {
  const int row = blockIdx.x * 256 + threadIdx.x;   // 0..2*NTOT-1
  float S0 = 0.f, S1 = 0.f, S2 = 0.f;
  #pragma unroll
  for (int p = 0; p < 32; ++p) {
    const float4 v = statsp[(size_t)row * 32 + p];
    S0 += v.x; S1 += v.y; S2 += v.z;
  }
  const float mu = S1 / S0;
  const float var = S2 / S0 - mu * mu;
  terms[row] = mu * mu / var + LAM * logf(var);
}

__global__ __launch_bounds__(256) void final_reduce_k(const float* __restrict__ terms,
                                                      float* __restrict__ out) {
  float s = 0.f;
  for (int i = threadIdx.x; i < 2 * NTOT; i += 256) s += terms[i];
  __shared__ float red[4];
  s = wave_sum64(s);
  if ((threadIdx.x & 63) == 0) red[threadIdx.x >> 6] = s;
  __syncthreads();
  if (threadIdx.x == 0) out[0] = (red[0] + red[1] + red[2] + red[3]) * (1.0f / (2.0f * NTOT));
}

extern "C" void kernel_launch(void* const* d_in, const int* in_sizes, int n_in,
                              void* d_out, int out_size, void* d_ws, size_t ws_size,
                              hipStream_t stream) {
  const float* a    = (const float*)d_in[0];
  const float* b    = (const float*)d_in[1];
  const float* idxa = (const float*)d_in[2];
  const float* idxb = (const float*)d_in[3];
  float* out = (float*)d_out;
  char* ws = (char*)d_ws;

  size_t off = 0;
  u16*    E    = (u16*)(ws + off);    off += 2 * (size_t)NTOT * NTOT * 2;   // 64 MB
  float*  Qp   = (float*)(ws + off);  off += 2 * 4 * (size_t)NTOT * CH * 4; // 32 MB
  u16*    Qb   = (u16*)(ws + off);    off += 2 * (size_t)NTOT * CH * 2;     // 4 MB
  u16*    abf  = (u16*)(ws + off);    off += (size_t)NTOT * CH * 2;
  u16*    bbf  = (u16*)(ws + off);    off += (size_t)NTOT * CH * 2;
  u16*    att  = (u16*)(ws + off);    off += (size_t)NTOT * CH * 2;
  u16*    btt  = (u16*)(ws + off);    off += (size_t)NTOT * CH * 2;
  float*  na   = (float*)(ws + off);  off += (size_t)NTOT * 4;
  float*  nb   = (float*)(ws + off);  off += (size_t)NTOT * 4;
  float*  dnp  = (float*)(ws + off);  off += 2 * (size_t)NTOT * 64 * 4;     // 2 MB
  float4* stp  = (float4*)(ws + off); off += 2 * (size_t)NTOT * 32 * 16;    // 4 MB
  float*  terms = (float*)(ws + off);

  cvt_norm_k<<<2 * NTOT, 64, 0, stream>>>(a, b, abf, bbf, na, nb);
  transpose2_k<<<dim3(CH / 32, NTOT / 32, 2), 256, 0, stream>>>(abf, bbf, att, btt);
  gemm_exp_k<<<1024, 256, 0, stream>>>(abf, bbf, na, nb, E, dnp);
  gemm_qp_k<<<512, 256, 0, stream>>>(E, att, btt, Qp);
  reduce_q_k<<<dim3(NTOT, 1, 2), 256, 0, stream>>>(Qp, dnp, Qb);
  flash_stats_k<<<1024, 256, 0, stream>>>(Qb, abf, bbf, na, nb, idxa, idxb, stp);
  stats_combine_k<<<2 * NTOT / 256, 256, 0, stream>>>(stp, terms);
  final_reduce_k<<<1, 256, 0, stream>>>(terms, out);
}

// Round 15
// 123.421 us; speedup vs baseline: 1.1390x; 1.0107x over previous
//
#include <hip/hip_runtime.h>

#define NTOT 4096
#define CH 256
#define SCALE 0.0390625f   // 1/(256*0.1)
#define LAM 0.001f

typedef unsigned short u16;
typedef __attribute__((ext_vector_type(8))) short short8;   // 8 bf16 (4 VGPRs)
typedef __attribute__((ext_vector_type(4))) float floatx4;  // MFMA acc

__device__ __forceinline__ float wave_sum64(float v) {
  #pragma unroll
  for (int o = 32; o; o >>= 1) v += __shfl_down(v, o, 64);
  return v;
}
__device__ __forceinline__ u16 f2bf(float f) {  // round-to-nearest-even
  unsigned u = __float_as_uint(f);
  u += 0x7fffu + ((u >> 16) & 1u);
  return (u16)(u >> 16);
}
__device__ __forceinline__ float bf2f(u16 h) {
  return __uint_as_float(((unsigned)h) << 16);
}
__device__ __forceinline__ void gload_lds(const u16* g, void* l) {
  __builtin_amdgcn_global_load_lds((const __attribute__((address_space(1))) void*)g,
                                   (__attribute__((address_space(3))) void*)l, 16, 0, 0);
}
__device__ __forceinline__ void mm4x4(const short8 (&av)[4], const short8 (&bv)[4],
                                      floatx4 (&acc)[4][4]) {
  #pragma unroll
  for (int m = 0; m < 4; ++m)
    #pragma unroll
    for (int n = 0; n < 4; ++n)
      acc[m][n] = __builtin_amdgcn_mfma_f32_16x16x32_bf16(av[m], bv[n], acc[m][n], 0, 0, 0);
}
// 128 B LDS rows: byte ^= (row&7)<<4 (verified rounds 6-14, conflicts -> 0)
__device__ __forceinline__ int swz128(int row) { return (row & 7) << 4; }

// f32 -> bf16 for both inputs + row norms of the ROUNDED values (one wave/row).
__global__ __launch_bounds__(64) void cvt_norm_k(const float* __restrict__ a,
                                                 const float* __restrict__ b,
                                                 u16* __restrict__ ab, u16* __restrict__ bb,
                                                 float* __restrict__ na, float* __restrict__ nb) {
  int row = blockIdx.x;
  const float* src; u16* dst; float* nd;
  if (row < NTOT) { src = a; dst = ab; nd = na; }
  else { row -= NTOT; src = b; dst = bb; nd = nb; }
  const float4 v = *reinterpret_cast<const float4*>(src + (size_t)row * CH + threadIdx.x * 4);
  const u16 h0 = f2bf(v.x), h1 = f2bf(v.y), h2 = f2bf(v.z), h3 = f2bf(v.w);
  uint2 st;
  st.x = (unsigned)h0 | ((unsigned)h1 << 16);
  st.y = (unsigned)h2 | ((unsigned)h3 << 16);
  *reinterpret_cast<uint2*>(dst + (size_t)row * CH + threadIdx.x * 4) = st;
  const float f0 = bf2f(h0), f1 = bf2f(h1), f2 = bf2f(h2), f3 = bf2f(h3);
  float s = f0 * f0 + f1 * f1 + f2 * f2 + f3 * f3;
  s = wave_sum64(s);
  if (threadIdx.x == 0) nd[row] = s;
}

// [4096][256] -> [256][4096] bf16 transpose for both inputs (z selects a/b)
__global__ __launch_bounds__(256) void transpose2_k(const u16* __restrict__ ab,
                                                    const u16* __restrict__ bb,
                                                    u16* __restrict__ at, u16* __restrict__ bt) {
  const u16* __restrict__ src = blockIdx.z ? bb : ab;
  u16* __restrict__ dst = blockIdx.z ? bt : at;
  __shared__ u16 t[32][33];
  const int bx = blockIdx.x * 32, by = blockIdx.y * 32;
  const int lx = threadIdx.x & 31, ly = threadIdx.x >> 5;
  #pragma unroll
  for (int i = 0; i < 32; i += 8)
    t[ly + i][lx] = src[(size_t)(by + ly + i) * CH + bx + lx];
  __syncthreads();
  #pragma unroll
  for (int i = 0; i < 32; i += 8)
    dst[(size_t)(bx + ly + i) * NTOT + by + lx] = t[lx][ly + i];
}

// ---------------------------------------------------------------------------
// SHARED-S phase-1 (round-13/14 verified GEMM core). NEW: BOTH E outputs are
// re-laid out in LDS after the K-loop and written as 256 B-contiguous short8
// row stores (Eab previously used 16 scalar u16 stores/thread = 32 B write
// segments). LDS 72 KB (stage dbuf reused as Lab/Lba) -> still 2 blocks/CU.
__global__ __launch_bounds__(256, 2) void gemm_exp_k(const u16* __restrict__ abf,
                                                     const u16* __restrict__ bbf,
                                                     const float* __restrict__ na,
                                                     const float* __restrict__ nb,
                                                     u16* __restrict__ E,
                                                     float* __restrict__ dnp) {
  const int wg = blockIdx.x;
  const int xcd = wg & 7;
  const int local = wg >> 3;                // [0,128)
  const int bx = xcd * 4 + (local & 3);     // b-col tile: 4 per XCD (256 KB)
  const int by = local >> 2;                // a-row tile [0,32): streams
  const int bn = bx * 128, bm = by * 128;
  u16* __restrict__ Eab = E;                                // [a-row][b-col]
  u16* __restrict__ Eba = E + (size_t)NTOT * NTOT;          // [b-row][a-col]
  float* __restrict__ dnp0 = dnp;                           // ab row sums
  float* __restrict__ dnp1 = dnp + (size_t)NTOT * 64;       // ba row sums

  __shared__ u16 smem[36864];   // 72 KB: As dbuf [0,32KB), Bs dbuf [32,64KB)
  const int tid = threadIdx.x, wid = tid >> 6, lane = tid & 63;
  const int wr = (wid >> 1) * 64, wc = (wid & 1) * 64;
  const int lr = lane & 15, g = lane >> 4;

  auto stage = [&](int t, int bi) {
    const int k0 = t * 64;
    #pragma unroll
    for (int i = 0; i < 4; ++i) {
      const int lb = (wid + 4 * i) * 1024;          // wave-uniform LDS byte base
      const int db = lb + lane * 16;                // lane's linear dest byte
      const int r = db >> 7;                        // dest row (128 B rows)
      const int cb = (db & 127) ^ swz128(r);        // inverse-swizzled source col
      gload_lds(abf + (size_t)(bm + r) * CH + k0 + (cb >> 1), (char*)smem + bi * 16384 + lb);
      gload_lds(bbf + (size_t)(bn + r) * CH + k0 + (cb >> 1), (char*)smem + 32768 + bi * 16384 + lb);
    }
  };

  floatx4 acc[4][4] = {};
  stage(0, 0);
  asm volatile("s_waitcnt vmcnt(0)" ::: "memory");
  __builtin_amdgcn_s_barrier();
  #pragma unroll
  for (int t = 0; t < 4; ++t) {
    if (t < 3) stage(t + 1, (t + 1) & 1);
    const int bi = t & 1;
    const char* Ab = (const char*)smem + bi * 16384;
    const char* Bb = (const char*)smem + 32768 + bi * 16384;
    #pragma unroll
    for (int ks = 0; ks < 2; ++ks) {
      const int ob = ks * 64 + g * 16;
      short8 af[4], bfr[4];
      #pragma unroll
      for (int m = 0; m < 4; ++m) {
        const int row = wr + m * 16 + lr;
        af[m] = *reinterpret_cast<const short8*>(Ab + row * 128 + (ob ^ swz128(row)));
      }
      #pragma unroll
      for (int n = 0; n < 4; ++n) {
        const int row = wc + n * 16 + lr;
        bfr[n] = *reinterpret_cast<const short8*>(Bb + row * 128 + (ob ^ swz128(row)));
      }
      mm4x4(af, bfr, acc);
    }
    if (t < 3) {
      asm volatile("s_waitcnt vmcnt(0)" ::: "memory");
      __builtin_amdgcn_s_barrier();
    }
  }
  __syncthreads();   // all LDS reads done -> buffers reusable for Lab/Lba
  // Lab: [128 a-rows][136] at u16-offset 0; Lba: [128 b-cols][136] at 17408.
  // 136-pad rows: stride 272 B -> 2-way bank aliasing on column writes (free).
  u16 (*Lab)[136] = reinterpret_cast<u16 (*)[136]>(smem);
  u16 (*Lba)[136] = reinterpret_cast<u16 (*)[136]>(smem + 17408);

  float nbv[4], nav[4][4];
  #pragma unroll
  for (int n = 0; n < 4; ++n) nbv[n] = nb[bn + wc + n * 16 + lr];
  #pragma unroll
  for (int m = 0; m < 4; ++m) {
    const int rowb = bm + wr + m * 16 + g * 4;
    #pragma unroll
    for (int r = 0; r < 4; ++r) nav[m][r] = na[rowb + r];
  }

  float rowsum[4][4] = {}, colsum[4] = {};
  #pragma unroll
  for (int m = 0; m < 4; ++m) {
    const int ilb = wr + m * 16 + g * 4;              // local a-row base
    #pragma unroll
    for (int n = 0; n < 4; ++n) {
      const int jl = wc + n * 16 + lr;                // local b-col
      #pragma unroll
      for (int r = 0; r < 4; ++r) {
        const float s2 = 2.f * acc[m][n][r];
        const float w0 = __expf((s2 - nbv[n]) * SCALE);       // dir ab
        Lab[ilb + r][jl] = f2bf(w0);
        rowsum[m][r] += w0;
        const float w1 = __expf((s2 - nav[m][r]) * SCALE);    // dir ba
        colsum[n] += w1;
        Lba[jl][ilb + r] = f2bf(w1);
      }
    }
  }
  // ab row sums -> dnp0 (layout unchanged)
  #pragma unroll
  for (int m = 0; m < 4; ++m) {
    const int rowb = bm + wr + m * 16 + g * 4;
    #pragma unroll
    for (int r = 0; r < 4; ++r) {
      float s = rowsum[m][r];
      #pragma unroll
      for (int o = 1; o < 16; o <<= 1) s += __shfl_xor(s, o, 64);
      if (lr == 0) dnp0[(size_t)(rowb + r) * 64 + bx * 2 + (wid & 1)] = s;
    }
  }
  // ba row sums (= tile col sums): reduce over g-groups (lanes ^16, ^32)
  #pragma unroll
  for (int n = 0; n < 4; ++n) {
    float v = colsum[n];
    v += __shfl_xor(v, 16, 64);
    v += __shfl_xor(v, 32, 64);
    if (g == 0)
      dnp1[(size_t)(bn + wc + n * 16 + lr) * 64 + by * 2 + (wid >> 1)] = v;
  }
  __syncthreads();
  // coalesced write-out of BOTH tiles: 16 threads/row, 256 B contiguous/row
  #pragma unroll
  for (int p = 0; p < 8; ++p) {
    const int rl = (tid >> 4) + p * 16;
    const int cl = (tid & 15) * 8;
    const short8 v0 = *reinterpret_cast<const short8*>(&Lab[rl][cl]);
    *reinterpret_cast<short8*>(&Eab[(size_t)(bm + rl) * NTOT + bn + cl]) = v0;
    const short8 v1 = *reinterpret_cast<const short8*>(&Lba[rl][cl]);
    *reinterpret_cast<short8*>(&Eba[(size_t)(bn + rl) * NTOT + bm + cl]) = v1;
  }
}

// ---------------------------------------------------------------------------
// Qp = E . Yt^T, split-K 4, both dirs (round-10 structure, XCD-pinned dk).
__global__ __launch_bounds__(256, 2) void gemm_qp_k(const u16* __restrict__ E,
                                                    const u16* __restrict__ att,
                                                    const u16* __restrict__ btt,
                                                    float* __restrict__ Qp) {
  const int wg = blockIdx.x;
  const int dk = wg & 7;
  const int j = wg >> 3;
  const int dir = dk >> 2, kz = dk & 3;
  const int bxi = j & 1, byi = j >> 1;

  const u16* __restrict__ A = E + (size_t)dir * NTOT * NTOT;
  const u16* __restrict__ B = dir ? att : btt;
  float* __restrict__ C = Qp + (size_t)dir * 4 * NTOT * CH + (size_t)kz * NTOT * CH;
  const int k0base = kz * (NTOT / 4);

  __shared__ u16 As[2][128][64];
  __shared__ u16 Bs[2][128][64];
  const int tid = threadIdx.x, wid = tid >> 6, lane = tid & 63;
  const int bn = bxi * 128, bm = byi * 128;
  const int wr = (wid >> 1) * 64, wc = (wid & 1) * 64;
  const int lr = lane & 15;

  auto stage = [&](int t, int bi) {
    const int k0 = k0base + t * 64;
    #pragma unroll
    for (int i = 0; i < 4; ++i) {
      const int lb = (wid + 4 * i) * 1024;
      const int db = lb + lane * 16;
      const int r = db >> 7;
      const int cb = (db & 127) ^ swz128(r);
      gload_lds(A + (size_t)(bm + r) * NTOT + k0 + (cb >> 1), (char*)&As[bi][0][0] + lb);
      gload_lds(B + (size_t)(bn + r) * NTOT + k0 + (cb >> 1), (char*)&Bs[bi][0][0] + lb);
    }
  };

  floatx4 acc[4][4] = {};
  stage(0, 0);
  asm volatile("s_waitcnt vmcnt(0)" ::: "memory");
  __builtin_amdgcn_s_barrier();
  for (int t = 0; t < 16; ++t) {
    if (t < 15) stage(t + 1, (t + 1) & 1);
    const int bi = t & 1;
    const char* Ab = (const char*)&As[bi][0][0];
    const char* Bb = (const char*)&Bs[bi][0][0];
    #pragma unroll
    for (int ks = 0; ks < 2; ++ks) {
      const int ob = ks * 64 + (lane >> 4) * 16;
      short8 af[4], bfr[4];
      #pragma unroll
      for (int m = 0; m < 4; ++m) {
        const int row = wr + m * 16 + lr;
        af[m] = *reinterpret_cast<const short8*>(Ab + row * 128 + (ob ^ swz128(row)));
      }
      #pragma unroll
      for (int n = 0; n < 4; ++n) {
        const int row = wc + n * 16 + lr;
        bfr[n] = *reinterpret_cast<const short8*>(Bb + row * 128 + (ob ^ swz128(row)));
      }
      mm4x4(af, bfr, acc);
    }
    asm volatile("s_waitcnt vmcnt(0)" ::: "memory");
    __builtin_amdgcn_s_barrier();
  }
  #pragma unroll
  for (int m = 0; m < 4; ++m) {
    const int row = bm + wr + m * 16 + (lane >> 4) * 4;
    #pragma unroll
    for (int n = 0; n < 4; ++n) {
      const int col = bn + wc + n * 16 + lr;
      #pragma unroll
      for (int r = 0; r < 4; ++r)
        C[(size_t)(row + r) * CH + col] = acc[m][n][r];
    }
  }
}

// Q = (sum of 4 split-K partials) / dn -> bf16. Block per row; both dirs via z.
__global__ __launch_bounds__(256) void reduce_q_k(const float* __restrict__ Qp,
                                                  const float* __restrict__ dnp,
                                                  u16* __restrict__ Qb) {
  const int dir = blockIdx.z;
  Qp += (size_t)dir * 4 * NTOT * CH;
  dnp += (size_t)dir * NTOT * 64;
  Qb += (size_t)dir * NTOT * CH;
  const int row = blockIdx.x, tid = threadIdx.x;
  __shared__ float sdn;
  if (tid < 64) {
    float s = dnp[(size_t)row * 64 + tid];
    s = wave_sum64(s);
    if (tid == 0) sdn = 1.0f / s;
  }
  __syncthreads();
  const float rdn = sdn;
  const size_t o = (size_t)row * CH + tid;
  const size_t st = (size_t)NTOT * CH;
  const float q = (Qp[o] + Qp[o + st] + Qp[o + 2 * st] + Qp[o + 3 * st]) * rdn;
  Qb[o] = f2bf(q);
}

// ---------------------------------------------------------------------------
// Phase-2 flash. NEW: 4 j-tiles per block (16-step loop, same dbuf staging):
// Qb staging traffic halves; loop reaches qp-like steady state. XCD xcd owns
// j-chunk bx = xcd (512 X-cols = 256 KB/dir, L2-resident); Qb streams.
__global__ __launch_bounds__(256, 2) void flash_stats_k(const u16* __restrict__ Qball,
                                                        const u16* __restrict__ abf,
                                                        const u16* __restrict__ bbf,
                                                        const float* __restrict__ na,
                                                        const float* __restrict__ nb,
                                                        const float* __restrict__ idxa,
                                                        const float* __restrict__ idxb,
                                                        float4* __restrict__ statsp) {
  const int wg = blockIdx.x;
  const int dir = wg >> 8;                  // 256 blocks per dir
  const int w = wg & 255;
  const int bx = w & 7;                     // j-chunk [0,8) = XCD id (256 KB)
  const int by = w >> 3;                    // bm [0,32): streams

  const u16* __restrict__ Qb = Qball + (size_t)dir * NTOT * CH;
  const u16* __restrict__ X = dir ? bbf : abf;
  const float* __restrict__ nx = dir ? nb : na;
  const float* __restrict__ idx = dir ? idxb : idxa;
  statsp += (size_t)dir * NTOT * 16;

  __shared__ u16 As[2][128][64];
  __shared__ u16 Bs[2][128][64];
  const int tid = threadIdx.x, wid = tid >> 6, lane = tid & 63;
  const int bm = by * 128;
  const int jbase = bx * 512;
  const int wr = (wid >> 1) * 64, wc = (wid & 1) * 64;
  const int lr = lane & 15;

  auto stage = [&](int t, int bi) {
    const int k0 = (t & 3) * 64;
    const int bn = jbase + (t >> 2) * 128;
    #pragma unroll
    for (int i = 0; i < 4; ++i) {
      const int lb = (wid + 4 * i) * 1024;
      const int db = lb + lane * 16;
      const int r = db >> 7;
      const int cb = (db & 127) ^ swz128(r);
      gload_lds(Qb + (size_t)(bm + r) * CH + k0 + (cb >> 1), (char*)&As[bi][0][0] + lb);
      gload_lds(X + (size_t)(bn + r) * CH + k0 + (cb >> 1), (char*)&Bs[bi][0][0] + lb);
    }
  };

  float cen[4][4];
  #pragma unroll
  for (int m = 0; m < 4; ++m) {
    const int rowb = bm + wr + m * 16 + (lane >> 4) * 4;
    #pragma unroll
    for (int r = 0; r < 4; ++r) cen[m][r] = idx[rowb + r];
  }
  float s0[4][4] = {}, s1[4][4] = {}, s2[4][4] = {};
  floatx4 acc[4][4] = {};

  stage(0, 0);
  asm volatile("s_waitcnt vmcnt(0)" ::: "memory");
  __builtin_amdgcn_s_barrier();
  for (int t = 0; t < 16; ++t) {
    if (t < 15) stage(t + 1, (t + 1) & 1);
    const int bi = t & 1;
    const char* Ab = (const char*)&As[bi][0][0];
    const char* Bb = (const char*)&Bs[bi][0][0];
    #pragma unroll
    for (int ks = 0; ks < 2; ++ks) {
      const int ob = ks * 64 + (lane >> 4) * 16;
      short8 af[4], bfr[4];
      #pragma unroll
      for (int m = 0; m < 4; ++m) {
        const int row = wr + m * 16 + lr;
        af[m] = *reinterpret_cast<const short8*>(Ab + row * 128 + (ob ^ swz128(row)));
      }
      #pragma unroll
      for (int n = 0; n < 4; ++n) {
        const int row = wc + n * 16 + lr;
        bfr[n] = *reinterpret_cast<const short8*>(Bb + row * 128 + (ob ^ swz128(row)));
      }
      mm4x4(af, bfr, acc);
    }
    if ((t & 3) == 3) {  // end of a j-tile: fold stats, reset acc
      const int bn = jbase + (t >> 2) * 128;
      #pragma unroll
      for (int n = 0; n < 4; ++n) {
        const int col = bn + wc + n * 16 + lr;
        const float nxv = nx[col];
        const float iv = idx[col];
        #pragma unroll
        for (int m = 0; m < 4; ++m) {
          #pragma unroll
          for (int r = 0; r < 4; ++r) {
            const float w2 = __expf((2.f * acc[m][n][r] - nxv) * SCALE);
            const float d = iv - cen[m][r];
            s0[m][r] += w2;
            s1[m][r] += w2 * d;
            s2[m][r] += w2 * d * d;
            acc[m][n][r] = 0.f;
          }
        }
      }
    }
    if (t < 15) {
      asm volatile("s_waitcnt vmcnt(0)" ::: "memory");
      __builtin_amdgcn_s_barrier();
    }
  }
  #pragma unroll
  for (int m = 0; m < 4; ++m) {
    const int rowb = bm + wr + m * 16 + (lane >> 4) * 4;
    #pragma unroll
    for (int r = 0; r < 4; ++r) {
      float a = s0[m][r], b = s1[m][r], c = s2[m][r];
      #pragma unroll
      for (int o = 1; o < 16; o <<= 1) {
        a += __shfl_xor(a, o, 64);
        b += __shfl_xor(b, o, 64);
        c += __shfl_xor(c, o, 64);
      }
      if (lr == 0)
        statsp[(size_t)(rowb + r) * 16 + bx * 2 + (wid & 1)] = make_float4(a, b, c, 0.f);
    }
  }
}

// per-row: combine 16 partials -> loss term. mu = S1/S0; var = S2/S0 - mu^2.
__global__ __launch_bounds__(256) void stats_combine_k(const float4* __restrict__ statsp,
                                                       float* __restrict__ terms) {
  const int row = blockIdx.x * 256 + threadIdx.x;   // 0..2*NTOT-1
  float S0 = 0.f, S1 = 0.f, S2 = 0.f;
  #pragma unroll
  for (int p = 0; p < 16; ++p) {
    const float4 v = statsp[(size_t)row * 16 + p];
    S0 += v.x; S1 += v.y; S2 += v.z;
  }
  const float mu = S1 / S0;
  const float var = S2 / S0 - mu * mu;
  terms[row] = mu * mu / var + LAM * logf(var);
}

__global__ __launch_bounds__(256) void final_reduce_k(const float* __restrict__ terms,
                                                      float* __restrict__ out) {
  float s = 0.f;
  for (int i = threadIdx.x; i < 2 * NTOT; i += 256) s += terms[i];
  __shared__ float red[4];
  s = wave_sum64(s);
  if ((threadIdx.x & 63) == 0) red[threadIdx.x >> 6] = s;
  __syncthreads();
  if (threadIdx.x == 0) out[0] = (red[0] + red[1] + red[2] + red[3]) * (1.0f / (2.0f * NTOT));
}

extern "C" void kernel_launch(void* const* d_in, const int* in_sizes, int n_in,
                              void* d_out, int out_size, void* d_ws, size_t ws_size,
                              hipStream_t stream) {
  const float* a    = (const float*)d_in[0];
  const float* b    = (const float*)d_in[1];
  const float* idxa = (const float*)d_in[2];
  const float* idxb = (const float*)d_in[3];
  float* out = (float*)d_out;
  char* ws = (char*)d_ws;

  size_t off = 0;
  u16*    E    = (u16*)(ws + off);    off += 2 * (size_t)NTOT * NTOT * 2;   // 64 MB
  float*  Qp   = (float*)(ws + off);  off += 2 * 4 * (size_t)NTOT * CH * 4; // 32 MB
  u16*    Qb   = (u16*)(ws + off);    off += 2 * (size_t)NTOT * CH * 2;     // 4 MB
  u16*    abf  = (u16*)(ws + off);    off += (size_t)NTOT * CH * 2;
  u16*    bbf  = (u16*)(ws + off);    off += (size_t)NTOT * CH * 2;
  u16*    att  = (u16*)(ws + off);    off += (size_t)NTOT * CH * 2;
  u16*    btt  = (u16*)(ws + off);    off += (size_t)NTOT * CH * 2;
  float*  na   = (float*)(ws + off);  off += (size_t)NTOT * 4;
  float*  nb   = (float*)(ws + off);  off += (size_t)NTOT * 4;
  float*  dnp  = (float*)(ws + off);  off += 2 * (size_t)NTOT * 64 * 4;     // 2 MB
  float4* stp  = (float4*)(ws + off); off += 2 * (size_t)NTOT * 16 * 16;    // 2 MB
  float*  terms = (float*)(ws + off);

  cvt_norm_k<<<2 * NTOT, 64, 0, stream>>>(a, b, abf, bbf, na, nb);
  transpose2_k<<<dim3(CH / 32, NTOT / 32, 2), 256, 0, stream>>>(abf, bbf, att, btt);
  gemm_exp_k<<<1024, 256, 0, stream>>>(abf, bbf, na, nb, E, dnp);
  gemm_qp_k<<<512, 256, 0, stream>>>(E, att, btt, Qp);
  reduce_q_k<<<dim3(NTOT, 1, 2), 256, 0, stream>>>(Qp, dnp, Qb);
  flash_stats_k<<<512, 256, 0, stream>>>(Qb, abf, bbf, na, nb, idxa, idxb, stp);
  stats_combine_k<<<2 * NTOT / 256, 256, 0, stream>>>(stp, terms);
  final_reduce_k<<<1, 256, 0, stream>>>(terms, out);
}

// Round 16
// 120.836 us; speedup vs baseline: 1.1633x; 1.0214x over previous
//
#include <hip/hip_runtime.h>

#define NTOT 4096
#define CH 256
#define SCALE 0.0390625f   // 1/(256*0.1)
#define LAM 0.001f

typedef unsigned short u16;
typedef __attribute__((ext_vector_type(8))) short short8;   // 8 bf16 (4 VGPRs)
typedef __attribute__((ext_vector_type(4))) float floatx4;  // MFMA acc

__device__ __forceinline__ float wave_sum64(float v) {
  #pragma unroll
  for (int o = 32; o; o >>= 1) v += __shfl_down(v, o, 64);
  return v;
}
__device__ __forceinline__ u16 f2bf(float f) {  // round-to-nearest-even
  unsigned u = __float_as_uint(f);
  u += 0x7fffu + ((u >> 16) & 1u);
  return (u16)(u >> 16);
}
__device__ __forceinline__ float bf2f(u16 h) {
  return __uint_as_float(((unsigned)h) << 16);
}
__device__ __forceinline__ void gload_lds(const u16* g, void* l) {
  __builtin_amdgcn_global_load_lds((const __attribute__((address_space(1))) void*)g,
                                   (__attribute__((address_space(3))) void*)l, 16, 0, 0);
}
__device__ __forceinline__ void mm4x4(const short8 (&av)[4], const short8 (&bv)[4],
                                      floatx4 (&acc)[4][4]) {
  #pragma unroll
  for (int m = 0; m < 4; ++m)
    #pragma unroll
    for (int n = 0; n < 4; ++n)
      acc[m][n] = __builtin_amdgcn_mfma_f32_16x16x32_bf16(av[m], bv[n], acc[m][n], 0, 0, 0);
}
// 128 B LDS rows: byte ^= (row&7)<<4 (verified rounds 6-15, conflicts -> 0)
__device__ __forceinline__ int swz128(int row) { return (row & 7) << 4; }

// f32 -> bf16 for both inputs + row norms of the ROUNDED values (one wave/row).
__global__ __launch_bounds__(64) void cvt_norm_k(const float* __restrict__ a,
                                                 const float* __restrict__ b,
                                                 u16* __restrict__ ab, u16* __restrict__ bb,
                                                 float* __restrict__ na, float* __restrict__ nb) {
  int row = blockIdx.x;
  const float* src; u16* dst; float* nd;
  if (row < NTOT) { src = a; dst = ab; nd = na; }
  else { row -= NTOT; src = b; dst = bb; nd = nb; }
  const float4 v = *reinterpret_cast<const float4*>(src + (size_t)row * CH + threadIdx.x * 4);
  const u16 h0 = f2bf(v.x), h1 = f2bf(v.y), h2 = f2bf(v.z), h3 = f2bf(v.w);
  uint2 st;
  st.x = (unsigned)h0 | ((unsigned)h1 << 16);
  st.y = (unsigned)h2 | ((unsigned)h3 << 16);
  *reinterpret_cast<uint2*>(dst + (size_t)row * CH + threadIdx.x * 4) = st;
  const float f0 = bf2f(h0), f1 = bf2f(h1), f2 = bf2f(h2), f3 = bf2f(h3);
  float s = f0 * f0 + f1 * f1 + f2 * f2 + f3 * f3;
  s = wave_sum64(s);
  if (threadIdx.x == 0) nd[row] = s;
}

// [4096][256] -> [256][4096] bf16 transpose for both inputs (z selects a/b)
__global__ __launch_bounds__(256) void transpose2_k(const u16* __restrict__ ab,
                                                    const u16* __restrict__ bb,
                                                    u16* __restrict__ at, u16* __restrict__ bt) {
  const u16* __restrict__ src = blockIdx.z ? bb : ab;
  u16* __restrict__ dst = blockIdx.z ? bt : at;
  __shared__ u16 t[32][33];
  const int bx = blockIdx.x * 32, by = blockIdx.y * 32;
  const int lx = threadIdx.x & 31, ly = threadIdx.x >> 5;
  #pragma unroll
  for (int i = 0; i < 32; i += 8)
    t[ly + i][lx] = src[(size_t)(by + ly + i) * CH + bx + lx];
  __syncthreads();
  #pragma unroll
  for (int i = 0; i < 32; i += 8)
    dst[(size_t)(bx + ly + i) * NTOT + by + lx] = t[lx][ly + i];
}

// ---------------------------------------------------------------------------
// SHARED-S phase-1 (round-13/14/15 verified). CHANGE: Lab/Lba row pad 136->132
// (264 B rows). Write-side bank stride becomes 66 = 2 (mod 32): Lab epilogue
// writes conflict-free, Lba column writes 8-way -> 4-way. Readout unchanged
// (256 B-contiguous short8 row stores for both E outputs).
__global__ __launch_bounds__(256, 2) void gemm_exp_k(const u16* __restrict__ abf,
                                                     const u16* __restrict__ bbf,
                                                     const float* __restrict__ na,
                                                     const float* __restrict__ nb,
                                                     u16* __restrict__ E,
                                                     float* __restrict__ dnp) {
  const int wg = blockIdx.x;
  const int xcd = wg & 7;
  const int local = wg >> 3;                // [0,128)
  const int bx = xcd * 4 + (local & 3);     // b-col tile: 4 per XCD (256 KB)
  const int by = local >> 2;                // a-row tile [0,32): streams
  const int bn = bx * 128, bm = by * 128;
  u16* __restrict__ Eab = E;                                // [a-row][b-col]
  u16* __restrict__ Eba = E + (size_t)NTOT * NTOT;          // [b-row][a-col]
  float* __restrict__ dnp0 = dnp;                           // ab row sums
  float* __restrict__ dnp1 = dnp + (size_t)NTOT * 64;       // ba row sums

  __shared__ u16 smem[33792];   // 66 KB: staging 64 KB; overlaid Lab+Lba 66 KB
  const int tid = threadIdx.x, wid = tid >> 6, lane = tid & 63;
  const int wr = (wid >> 1) * 64, wc = (wid & 1) * 64;
  const int lr = lane & 15, g = lane >> 4;

  auto stage = [&](int t, int bi) {
    const int k0 = t * 64;
    #pragma unroll
    for (int i = 0; i < 4; ++i) {
      const int lb = (wid + 4 * i) * 1024;          // wave-uniform LDS byte base
      const int db = lb + lane * 16;                // lane's linear dest byte
      const int r = db >> 7;                        // dest row (128 B rows)
      const int cb = (db & 127) ^ swz128(r);        // inverse-swizzled source col
      gload_lds(abf + (size_t)(bm + r) * CH + k0 + (cb >> 1), (char*)smem + bi * 16384 + lb);
      gload_lds(bbf + (size_t)(bn + r) * CH + k0 + (cb >> 1), (char*)smem + 32768 + bi * 16384 + lb);
    }
  };

  floatx4 acc[4][4] = {};
  stage(0, 0);
  asm volatile("s_waitcnt vmcnt(0)" ::: "memory");
  __builtin_amdgcn_s_barrier();
  #pragma unroll
  for (int t = 0; t < 4; ++t) {
    if (t < 3) stage(t + 1, (t + 1) & 1);
    const int bi = t & 1;
    const char* Ab = (const char*)smem + bi * 16384;
    const char* Bb = (const char*)smem + 32768 + bi * 16384;
    #pragma unroll
    for (int ks = 0; ks < 2; ++ks) {
      const int ob = ks * 64 + g * 16;
      short8 af[4], bfr[4];
      #pragma unroll
      for (int m = 0; m < 4; ++m) {
        const int row = wr + m * 16 + lr;
        af[m] = *reinterpret_cast<const short8*>(Ab + row * 128 + (ob ^ swz128(row)));
      }
      #pragma unroll
      for (int n = 0; n < 4; ++n) {
        const int row = wc + n * 16 + lr;
        bfr[n] = *reinterpret_cast<const short8*>(Bb + row * 128 + (ob ^ swz128(row)));
      }
      mm4x4(af, bfr, acc);
    }
    if (t < 3) {
      asm volatile("s_waitcnt vmcnt(0)" ::: "memory");
      __builtin_amdgcn_s_barrier();
    }
  }
  __syncthreads();   // all LDS reads done -> buffers reusable for Lab/Lba
  // Lab: [128][132] u16 at offset 0; Lba: [128][132] at u16-offset 16896.
  // 264 B rows: bank stride 66 = 2 mod 32 -> Lab writes free, Lba 4-way.
  u16 (*Lab)[132] = reinterpret_cast<u16 (*)[132]>(smem);
  u16 (*Lba)[132] = reinterpret_cast<u16 (*)[132]>(smem + 16896);

  float nbv[4], nav[4][4];
  #pragma unroll
  for (int n = 0; n < 4; ++n) nbv[n] = nb[bn + wc + n * 16 + lr];
  #pragma unroll
  for (int m = 0; m < 4; ++m) {
    const int rowb = bm + wr + m * 16 + g * 4;
    #pragma unroll
    for (int r = 0; r < 4; ++r) nav[m][r] = na[rowb + r];
  }

  float rowsum[4][4] = {}, colsum[4] = {};
  #pragma unroll
  for (int m = 0; m < 4; ++m) {
    const int ilb = wr + m * 16 + g * 4;              // local a-row base
    #pragma unroll
    for (int n = 0; n < 4; ++n) {
      const int jl = wc + n * 16 + lr;                // local b-col
      #pragma unroll
      for (int r = 0; r < 4; ++r) {
        const float s2 = 2.f * acc[m][n][r];
        const float w0 = __expf((s2 - nbv[n]) * SCALE);       // dir ab
        Lab[ilb + r][jl] = f2bf(w0);
        rowsum[m][r] += w0;
        const float w1 = __expf((s2 - nav[m][r]) * SCALE);    // dir ba
        colsum[n] += w1;
        Lba[jl][ilb + r] = f2bf(w1);
      }
    }
  }
  // ab row sums -> dnp0 (layout unchanged)
  #pragma unroll
  for (int m = 0; m < 4; ++m) {
    const int rowb = bm + wr + m * 16 + g * 4;
    #pragma unroll
    for (int r = 0; r < 4; ++r) {
      float s = rowsum[m][r];
      #pragma unroll
      for (int o = 1; o < 16; o <<= 1) s += __shfl_xor(s, o, 64);
      if (lr == 0) dnp0[(size_t)(rowb + r) * 64 + bx * 2 + (wid & 1)] = s;
    }
  }
  // ba row sums (= tile col sums): reduce over g-groups (lanes ^16, ^32)
  #pragma unroll
  for (int n = 0; n < 4; ++n) {
    float v = colsum[n];
    v += __shfl_xor(v, 16, 64);
    v += __shfl_xor(v, 32, 64);
    if (g == 0)
      dnp1[(size_t)(bn + wc + n * 16 + lr) * 64 + by * 2 + (wid >> 1)] = v;
  }
  __syncthreads();
  // coalesced write-out of BOTH tiles: 16 threads/row, 256 B contiguous/row
  #pragma unroll
  for (int p = 0; p < 8; ++p) {
    const int rl = (tid >> 4) + p * 16;
    const int cl = (tid & 15) * 8;
    const short8 v0 = *reinterpret_cast<const short8*>(&Lab[rl][cl]);
    *reinterpret_cast<short8*>(&Eab[(size_t)(bm + rl) * NTOT + bn + cl]) = v0;
    const short8 v1 = *reinterpret_cast<const short8*>(&Lba[rl][cl]);
    *reinterpret_cast<short8*>(&Eba[(size_t)(bn + rl) * NTOT + bm + cl]) = v1;
  }
}

// ---------------------------------------------------------------------------
// Qp = E . Yt^T, split-K 4, both dirs (round-10 structure, XCD-pinned dk).
__global__ __launch_bounds__(256, 2) void gemm_qp_k(const u16* __restrict__ E,
                                                    const u16* __restrict__ att,
                                                    const u16* __restrict__ btt,
                                                    float* __restrict__ Qp) {
  const int wg = blockIdx.x;
  const int dk = wg & 7;
  const int j = wg >> 3;
  const int dir = dk >> 2, kz = dk & 3;
  const int bxi = j & 1, byi = j >> 1;

  const u16* __restrict__ A = E + (size_t)dir * NTOT * NTOT;
  const u16* __restrict__ B = dir ? att : btt;
  float* __restrict__ C = Qp + (size_t)dir * 4 * NTOT * CH + (size_t)kz * NTOT * CH;
  const int k0base = kz * (NTOT / 4);

  __shared__ u16 As[2][128][64];
  __shared__ u16 Bs[2][128][64];
  const int tid = threadIdx.x, wid = tid >> 6, lane = tid & 63;
  const int bn = bxi * 128, bm = byi * 128;
  const int wr = (wid >> 1) * 64, wc = (wid & 1) * 64;
  const int lr = lane & 15;

  auto stage = [&](int t, int bi) {
    const int k0 = k0base + t * 64;
    #pragma unroll
    for (int i = 0; i < 4; ++i) {
      const int lb = (wid + 4 * i) * 1024;
      const int db = lb + lane * 16;
      const int r = db >> 7;
      const int cb = (db & 127) ^ swz128(r);
      gload_lds(A + (size_t)(bm + r) * NTOT + k0 + (cb >> 1), (char*)&As[bi][0][0] + lb);
      gload_lds(B + (size_t)(bn + r) * NTOT + k0 + (cb >> 1), (char*)&Bs[bi][0][0] + lb);
    }
  };

  floatx4 acc[4][4] = {};
  stage(0, 0);
  asm volatile("s_waitcnt vmcnt(0)" ::: "memory");
  __builtin_amdgcn_s_barrier();
  for (int t = 0; t < 16; ++t) {
    if (t < 15) stage(t + 1, (t + 1) & 1);
    const int bi = t & 1;
    const char* Ab = (const char*)&As[bi][0][0];
    const char* Bb = (const char*)&Bs[bi][0][0];
    #pragma unroll
    for (int ks = 0; ks < 2; ++ks) {
      const int ob = ks * 64 + (lane >> 4) * 16;
      short8 af[4], bfr[4];
      #pragma unroll
      for (int m = 0; m < 4; ++m) {
        const int row = wr + m * 16 + lr;
        af[m] = *reinterpret_cast<const short8*>(Ab + row * 128 + (ob ^ swz128(row)));
      }
      #pragma unroll
      for (int n = 0; n < 4; ++n) {
        const int row = wc + n * 16 + lr;
        bfr[n] = *reinterpret_cast<const short8*>(Bb + row * 128 + (ob ^ swz128(row)));
      }
      mm4x4(af, bfr, acc);
    }
    asm volatile("s_waitcnt vmcnt(0)" ::: "memory");
    __builtin_amdgcn_s_barrier();
  }
  #pragma unroll
  for (int m = 0; m < 4; ++m) {
    const int row = bm + wr + m * 16 + (lane >> 4) * 4;
    #pragma unroll
    for (int n = 0; n < 4; ++n) {
      const int col = bn + wc + n * 16 + lr;
      #pragma unroll
      for (int r = 0; r < 4; ++r)
        C[(size_t)(row + r) * CH + col] = acc[m][n][r];
    }
  }
}

// Q = (sum of 4 split-K partials) / dn -> bf16. Block per row; both dirs via z.
__global__ __launch_bounds__(256) void reduce_q_k(const float* __restrict__ Qp,
                                                  const float* __restrict__ dnp,
                                                  u16* __restrict__ Qb) {
  const int dir = blockIdx.z;
  Qp += (size_t)dir * 4 * NTOT * CH;
  dnp += (size_t)dir * NTOT * 64;
  Qb += (size_t)dir * NTOT * CH;
  const int row = blockIdx.x, tid = threadIdx.x;
  __shared__ float sdn;
  if (tid < 64) {
    float s = dnp[(size_t)row * 64 + tid];
    s = wave_sum64(s);
    if (tid == 0) sdn = 1.0f / s;
  }
  __syncthreads();
  const float rdn = sdn;
  const size_t o = (size_t)row * CH + tid;
  const size_t st = (size_t)NTOT * CH;
  const float q = (Qp[o] + Qp[o + st] + Qp[o + 2 * st] + Qp[o + 3 * st]) * rdn;
  Qb[o] = f2bf(q);
}

// ---------------------------------------------------------------------------
// Phase-2 flash (round-15 verified): 4 j-tiles per block, 16-step loop.
// XCD xcd owns j-chunk bx = xcd (512 X-cols = 256 KB/dir); Qb streams.
__global__ __launch_bounds__(256, 2) void flash_stats_k(const u16* __restrict__ Qball,
                                                        const u16* __restrict__ abf,
                                                        const u16* __restrict__ bbf,
                                                        const float* __restrict__ na,
                                                        const float* __restrict__ nb,
                                                        const float* __restrict__ idxa,
                                                        const float* __restrict__ idxb,
                                                        float4* __restrict__ statsp) {
  const int wg = blockIdx.x;
  const int dir = wg >> 8;                  // 256 blocks per dir
  const int w = wg & 255;
  const int bx = w & 7;                     // j-chunk [0,8) = XCD id (256 KB)
  const int by = w >> 3;                    // bm [0,32): streams

  const u16* __restrict__ Qb = Qball + (size_t)dir * NTOT * CH;
  const u16* __restrict__ X = dir ? bbf : abf;
  const float* __restrict__ nx = dir ? nb : na;
  const float* __restrict__ idx = dir ? idxb : idxa;
  statsp += (size_t)dir * NTOT * 16;

  __shared__ u16 As[2][128][64];
  __shared__ u16 Bs[2][128][64];
  const int tid = threadIdx.x, wid = tid >> 6, lane = tid & 63;
  const int bm = by * 128;
  const int jbase = bx * 512;
  const int wr = (wid >> 1) * 64, wc = (wid & 1) * 64;
  const int lr = lane & 15;

  auto stage = [&](int t, int bi) {
    const int k0 = (t & 3) * 64;
    const int bn = jbase + (t >> 2) * 128;
    #pragma unroll
    for (int i = 0; i < 4; ++i) {
      const int lb = (wid + 4 * i) * 1024;
      const int db = lb + lane * 16;
      const int r = db >> 7;
      const int cb = (db & 127) ^ swz128(r);
      gload_lds(Qb + (size_t)(bm + r) * CH + k0 + (cb >> 1), (char*)&As[bi][0][0] + lb);
      gload_lds(X + (size_t)(bn + r) * CH + k0 + (cb >> 1), (char*)&Bs[bi][0][0] + lb);
    }
  };

  float cen[4][4];
  #pragma unroll
  for (int m = 0; m < 4; ++m) {
    const int rowb = bm + wr + m * 16 + (lane >> 4) * 4;
    #pragma unroll
    for (int r = 0; r < 4; ++r) cen[m][r] = idx[rowb + r];
  }
  float s0[4][4] = {}, s1[4][4] = {}, s2[4][4] = {};
  floatx4 acc[4][4] = {};

  stage(0, 0);
  asm volatile("s_waitcnt vmcnt(0)" ::: "memory");
  __builtin_amdgcn_s_barrier();
  for (int t = 0; t < 16; ++t) {
    if (t < 15) stage(t + 1, (t + 1) & 1);
    const int bi = t & 1;
    const char* Ab = (const char*)&As[bi][0][0];
    const char* Bb = (const char*)&Bs[bi][0][0];
    #pragma unroll
    for (int ks = 0; ks < 2; ++ks) {
      const int ob = ks * 64 + (lane >> 4) * 16;
      short8 af[4], bfr[4];
      #pragma unroll
      for (int m = 0; m < 4; ++m) {
        const int row = wr + m * 16 + lr;
        af[m] = *reinterpret_cast<const short8*>(Ab + row * 128 + (ob ^ swz128(row)));
      }
      #pragma unroll
      for (int n = 0; n < 4; ++n) {
        const int row = wc + n * 16 + lr;
        bfr[n] = *reinterpret_cast<const short8*>(Bb + row * 128 + (ob ^ swz128(row)));
      }
      mm4x4(af, bfr, acc);
    }
    if ((t & 3) == 3) {  // end of a j-tile: fold stats, reset acc
      const int bn = jbase + (t >> 2) * 128;
      #pragma unroll
      for (int n = 0; n < 4; ++n) {
        const int col = bn + wc + n * 16 + lr;
        const float nxv = nx[col];
        const float iv = idx[col];
        #pragma unroll
        for (int m = 0; m < 4; ++m) {
          #pragma unroll
          for (int r = 0; r < 4; ++r) {
            const float w2 = __expf((2.f * acc[m][n][r] - nxv) * SCALE);
            const float d = iv - cen[m][r];
            s0[m][r] += w2;
            s1[m][r] += w2 * d;
            s2[m][r] += w2 * d * d;
            acc[m][n][r] = 0.f;
          }
        }
      }
    }
    if (t < 15) {
      asm volatile("s_waitcnt vmcnt(0)" ::: "memory");
      __builtin_amdgcn_s_barrier();
    }
  }
  #pragma unroll
  for (int m = 0; m < 4; ++m) {
    const int rowb = bm + wr + m * 16 + (lane >> 4) * 4;
    #pragma unroll
    for (int r = 0; r < 4; ++r) {
      float a = s0[m][r], b = s1[m][r], c = s2[m][r];
      #pragma unroll
      for (int o = 1; o < 16; o <<= 1) {
        a += __shfl_xor(a, o, 64);
        b += __shfl_xor(b, o, 64);
        c += __shfl_xor(c, o, 64);
      }
      if (lr == 0)
        statsp[(size_t)(rowb + r) * 16 + bx * 2 + (wid & 1)] = make_float4(a, b, c, 0.f);
    }
  }
}

// per-row: combine 16 partials -> loss term. mu = S1/S0; var = S2/S0 - mu^2.
__global__ __launch_bounds__(256) void stats_combine_k(const float4* __restrict__ statsp,
                                                       float* __restrict__ terms) {
  const int row = blockIdx.x * 256 + threadIdx.x;   // 0..2*NTOT-1
  float S0 = 0.f, S1 = 0.f, S2 = 0.f;
  #pragma unroll
  for (int p = 0; p < 16; ++p) {
    const float4 v = statsp[(size_t)row * 16 + p];
    S0 += v.x; S1 += v.y; S2 += v.z;
  }
  const float mu = S1 / S0;
  const float var = S2 / S0 - mu * mu;
  terms[row] = mu * mu / var + LAM * logf(var);
}

__global__ __launch_bounds__(256) void final_reduce_k(const float* __restrict__ terms,
                                                      float* __restrict__ out) {
  float s = 0.f;
  for (int i = threadIdx.x; i < 2 * NTOT; i += 256) s += terms[i];
  __shared__ float red[4];
  s = wave_sum64(s);
  if ((threadIdx.x & 63) == 0) red[threadIdx.x >> 6] = s;
  __syncthreads();
  if (threadIdx.x == 0) out[0] = (red[0] + red[1] + red[2] + red[3]) * (1.0f / (2.0f * NTOT));
}

extern "C" void kernel_launch(void* const* d_in, const int* in_sizes, int n_in,
                              void* d_out, int out_size, void* d_ws, size_t ws_size,
                              hipStream_t stream) {
  const float* a    = (const float*)d_in[0];
  const float* b    = (const float*)d_in[1];
  const float* idxa = (const float*)d_in[2];
  const float* idxb = (const float*)d_in[3];
  float* out = (float*)d_out;
  char* ws = (char*)d_ws;

  size_t off = 0;
  u16*    E    = (u16*)(ws + off);    off += 2 * (size_t)NTOT * NTOT * 2;   // 64 MB
  float*  Qp   = (float*)(ws + off);  off += 2 * 4 * (size_t)NTOT * CH * 4; // 32 MB
  u16*    Qb   = (u16*)(ws + off);    off += 2 * (size_t)NTOT * CH * 2;     // 4 MB
  u16*    abf  = (u16*)(ws + off);    off += (size_t)NTOT * CH * 2;
  u16*    bbf  = (u16*)(ws + off);    off += (size_t)NTOT * CH * 2;
  u16*    att  = (u16*)(ws + off);    off += (size_t)NTOT * CH * 2;
  u16*    btt  = (u16*)(ws + off);    off += (size_t)NTOT * CH * 2;
  float*  na   = (float*)(ws + off);  off += (size_t)NTOT * 4;
  float*  nb   = (float*)(ws + off);  off += (size_t)NTOT * 4;
  float*  dnp  = (float*)(ws + off);  off += 2 * (size_t)NTOT * 64 * 4;     // 2 MB
  float4* stp  = (float4*)(ws + off); off += 2 * (size_t)NTOT * 16 * 16;    // 2 MB
  float*  terms = (float*)(ws + off);

  cvt_norm_k<<<2 * NTOT, 64, 0, stream>>>(a, b, abf, bbf, na, nb);
  transpose2_k<<<dim3(CH / 32, NTOT / 32, 2), 256, 0, stream>>>(abf, bbf, att, btt);
  gemm_exp_k<<<1024, 256, 0, stream>>>(abf, bbf, na, nb, E, dnp);
  gemm_qp_k<<<512, 256, 0, stream>>>(E, att, btt, Qp);
  reduce_q_k<<<dim3(NTOT, 1, 2), 256, 0, stream>>>(Qp, dnp, Qb);
  flash_stats_k<<<512, 256, 0, stream>>>(Qb, abf, bbf, na, nb, idxa, idxb, stp);
  stats_combine_k<<<2 * NTOT / 256, 256, 0, stream>>>(stp, terms);
  final_reduce_k<<<1, 256, 0, stream>>>(terms, out);
}